// Round 3
// baseline (314.374 us; speedup 1.0000x reference)
//
#include <hip/hip_runtime.h>
#include <hip/hip_bf16.h>

#define B_ 4
#define L_ 2048
#define D_ 1024
#define F_ 4096
#define H_ 16
#define E_ 64

typedef __hip_bfloat16 bf16;
typedef __attribute__((ext_vector_type(8))) short short8;
typedef __attribute__((ext_vector_type(4))) float f32x4;
typedef __attribute__((ext_vector_type(16))) float f32x16;

__device__ __forceinline__ short f2bf(float f) {
    union { float f; unsigned u; } v;
    v.f = f;
    unsigned r = (v.u + 0x7fff + ((v.u >> 16) & 1)) >> 16;
    return (short)r;
}

// async global->LDS, 16B per lane, lands at ldsbase + lane*16
__device__ __forceinline__ void gl_lds16(const short* g, short* l) {
    __builtin_amdgcn_global_load_lds((const __attribute__((address_space(1))) void*)g,
                                     (__attribute__((address_space(3))) void*)l, 16, 0, 0);
}

// ---------------- fp32 -> bf16 convert ----------------
__global__ __launch_bounds__(256) void convert_bf16_kernel(const float* __restrict__ src,
                                                           bf16* __restrict__ dst, int n) {
    int i = (blockIdx.x * 256 + threadIdx.x) * 4;
    if (i + 3 < n) {
        float4 v = *(const float4*)(src + i);
        dst[i + 0] = __float2bfloat16(v.x);
        dst[i + 1] = __float2bfloat16(v.y);
        dst[i + 2] = __float2bfloat16(v.z);
        dst[i + 3] = __float2bfloat16(v.w);
    }
}

// ---------------- V^T pre-pass + bf16 x copy ----------------
__global__ __launch_bounds__(256) void transpose_vt_kernel(const float* __restrict__ x,
                                                           short* __restrict__ vt,
                                                           short* __restrict__ xb) {
    __shared__ float tile[64][65];
    const int bh = blockIdx.x, lt = blockIdx.y;
    const int b = bh >> 4, h = bh & 15;
    const int l0 = lt * 64;
    for (int idx = threadIdx.x; idx < 4096; idx += 256) {
        int r = idx >> 6, c = idx & 63;
        float v = x[((size_t)b * L_ + l0 + r) * D_ + h * E_ + c];
        tile[r][c] = v;
        xb[((size_t)b * L_ + l0 + r) * D_ + h * E_ + c] = f2bf(v);
    }
    __syncthreads();
    for (int idx = threadIdx.x; idx < 4096; idx += 256) {
        int e = idx >> 6, l = idx & 63;
        vt[((size_t)bh * E_ + e) * L_ + l0 + l] = f2bf(tile[l][e]);
    }
}

// ---------------- flash attention, swapped-operand 32x32 MFMA, in-register P ----------------
// grid: (B*H)*16 blocks; 256 thr = 4 waves; block = 128 Q rows (32/wave); S-tile = 64.
// QK^T computed swapped: P^T = mfma_32x32x16(K, Q^T)  -> each lane owns one q-column.
// P^T redistributed in-register (cvt_pk + shfl_xor) to B-fragments; O^T = mfma(V^T, P^T).
// No P LDS round-trip; K/V double-buffered -> ONE barrier per s-tile.
__global__ __launch_bounds__(256, 3) void flash_attn_kernel(const float* __restrict__ x,
                                                            const short* __restrict__ xb,
                                                            const short* __restrict__ vt,
                                                            float* __restrict__ attn_out) {
    __shared__ short Ks[2][64][72];   // [buf][s][e]
    __shared__ short Vs[2][64][72];   // [buf][e][s]

    const int tid = threadIdx.x;
    const int w = tid >> 6, lane = tid & 63;
    const int l31 = lane & 31;
    const int hi = lane >> 5;         // 0/1: which k-half of fragments this lane holds
    const int hi8 = hi * 8;
    const int qt = blockIdx.x & 15;
    const int bh = blockIdx.x >> 4;
    const int b = bh >> 4, h = bh & 15;
    const int q0 = qt * 128;

    const short* kbase = xb + (size_t)b * L_ * D_ + h * E_;

    // Q as B-fragment of the swapped QK: lane holds Q[q=lane&31][e = ks*16 + hi*8 + 0..7]
    // scale/8 * log2(e) folded into the single bf16 rounding
    const float QS = 0.125f * 1.44269504f;
    const int qrow = q0 + w * 32 + l31;
    short8 qf[4];
    {
        const float* qp = x + ((size_t)b * L_ + qrow) * D_ + h * E_;
#pragma unroll
        for (int ks = 0; ks < 4; ks++) {
            float4 v0 = *(const float4*)(qp + ks * 16 + hi8);
            float4 v1 = *(const float4*)(qp + ks * 16 + hi8 + 4);
            short8 sc;
            sc[0] = f2bf(v0.x * QS); sc[1] = f2bf(v0.y * QS);
            sc[2] = f2bf(v0.z * QS); sc[3] = f2bf(v0.w * QS);
            sc[4] = f2bf(v1.x * QS); sc[5] = f2bf(v1.y * QS);
            sc[6] = f2bf(v1.z * QS); sc[7] = f2bf(v1.w * QS);
            qf[ks] = sc;
        }
    }

    // ones A-fragment for the l-sum MFMA (bf16 1.0 = 0x3F80)
    short8 ones;
#pragma unroll
    for (int z = 0; z < 8; z++) ones[z] = (short)0x3F80;

    f32x16 acc_o[2];   // O^T tiles: e in [0,32)+32*et (C rows), q = lane&31 (C col)
    f32x16 acc_l;      // l per q (every C row identical)
#pragma unroll
    for (int r = 0; r < 16; r++) { acc_o[0][r] = 0.f; acc_o[1][r] = 0.f; acc_l[r] = 0.f; }

    const int krow = tid >> 2, kseg = (tid & 3) * 16;  // staging: 4 thr/row, 32 B each

    // prologue: tile 0 -> regs -> buf0
    int4 rk0, rk1, rv0, rv1;
    {
        const short* ks = kbase + (size_t)krow * D_ + kseg;
        rk0 = *(const int4*)ks;
        rk1 = *(const int4*)(ks + 8);
        const short* vs = vt + ((size_t)bh * E_ + krow) * L_ + kseg;
        rv0 = *(const int4*)vs;
        rv1 = *(const int4*)(vs + 8);
    }
    *(int4*)&Ks[0][krow][kseg] = rk0;
    *(int4*)&Ks[0][krow][kseg + 8] = rk1;
    *(int4*)&Vs[0][krow][kseg] = rv0;
    *(int4*)&Vs[0][krow][kseg + 8] = rv1;

    for (int t = 0; t < L_ / 64; t++) {
        const int cur = t & 1;
        __syncthreads();  // buf[cur] writes visible; everyone done reading buf[cur^1]

        // issue next-tile global loads NOW; they complete under the compute below
        if (t + 1 < L_ / 64) {
            const short* ks = kbase + (size_t)((t + 1) * 64 + krow) * D_ + kseg;
            rk0 = *(const int4*)ks;
            rk1 = *(const int4*)(ks + 8);
            const short* vs = vt + ((size_t)bh * E_ + krow) * L_ + (t + 1) * 64 + kseg;
            rv0 = *(const int4*)vs;
            rv1 = *(const int4*)(vs + 8);
        }

        // P^T = K · Q^T : C[row=s][col=q], s = (r&3)+8*(r>>2)+4*hi (+32*stile)
        f32x16 accp0, accp1;
#pragma unroll
        for (int r = 0; r < 16; r++) { accp0[r] = 0.f; accp1[r] = 0.f; }
        __builtin_amdgcn_s_setprio(1);
#pragma unroll
        for (int ks = 0; ks < 4; ks++) {
            short8 kf0 = *(const short8*)&Ks[cur][l31][ks * 16 + hi8];
            short8 kf1 = *(const short8*)&Ks[cur][32 + l31][ks * 16 + hi8];
            accp0 = __builtin_amdgcn_mfma_f32_32x32x16_bf16(kf0, qf[ks], accp0, 0, 0, 0);
            accp1 = __builtin_amdgcn_mfma_f32_32x32x16_bf16(kf1, qf[ks], accp1, 0, 0, 0);
        }
        __builtin_amdgcn_s_setprio(0);

        // P = exp2(S') in-register
        float pe[2][16];
#pragma unroll
        for (int r = 0; r < 16; r++) {
            pe[0][r] = __builtin_amdgcn_exp2f(accp0[r]);
            pe[1][r] = __builtin_amdgcn_exp2f(accp1[r]);
        }

        // per 16-s block: pack to bf16, redistribute across the hi-pair, feed PV + l MFMAs.
        // B-frag needs k16 = hi*8+e with s = k2*16+k16; C-layout gave s=(r&3)+8(r>>2)+4hs.
        // -> target elems eh=0 come from hs=0 lanes, eh=1 from hs=1 lanes;
        //    reg group = {8*(k2&1) + 4*hi_target + 0..3}.
#pragma unroll
        for (int k2 = 0; k2 < 4; k2++) {
            const int tt = k2 >> 1, o = (k2 & 1) * 8;
            unsigned X0, X1, Y0, Y1;
            asm("v_cvt_pk_bf16_f32 %0, %1, %2" : "=v"(X0) : "v"(pe[tt][o + 0]), "v"(pe[tt][o + 1]));
            asm("v_cvt_pk_bf16_f32 %0, %1, %2" : "=v"(X1) : "v"(pe[tt][o + 2]), "v"(pe[tt][o + 3]));
            asm("v_cvt_pk_bf16_f32 %0, %1, %2" : "=v"(Y0) : "v"(pe[tt][o + 4]), "v"(pe[tt][o + 5]));
            asm("v_cvt_pk_bf16_f32 %0, %1, %2" : "=v"(Y1) : "v"(pe[tt][o + 6]), "v"(pe[tt][o + 7]));
            unsigned sx0 = (unsigned)__shfl_xor((int)X0, 32, 64);
            unsigned sx1 = (unsigned)__shfl_xor((int)X1, 32, 64);
            unsigned sy0 = (unsigned)__shfl_xor((int)Y0, 32, 64);
            unsigned sy1 = (unsigned)__shfl_xor((int)Y1, 32, 64);
            unsigned w0 = hi ? sy0 : X0;   // elems 0,1
            unsigned w1 = hi ? sy1 : X1;   // elems 2,3
            unsigned w2 = hi ? Y0 : sx0;   // elems 4,5
            unsigned w3 = hi ? Y1 : sx1;   // elems 6,7
            int4 wi = make_int4((int)w0, (int)w1, (int)w2, (int)w3);
            short8 pb = *(short8*)&wi;

            __builtin_amdgcn_s_setprio(1);
            acc_l = __builtin_amdgcn_mfma_f32_32x32x16_bf16(ones, pb, acc_l, 0, 0, 0);
            short8 vf0 = *(const short8*)&Vs[cur][l31][k2 * 16 + hi8];
            short8 vf1 = *(const short8*)&Vs[cur][32 + l31][k2 * 16 + hi8];
            acc_o[0] = __builtin_amdgcn_mfma_f32_32x32x16_bf16(vf0, pb, acc_o[0], 0, 0, 0);
            acc_o[1] = __builtin_amdgcn_mfma_f32_32x32x16_bf16(vf1, pb, acc_o[1], 0, 0, 0);
            __builtin_amdgcn_s_setprio(0);
        }

        // write staged regs -> other buffer (vmcnt drain covered by the compute above)
        if (t + 1 < L_ / 64) {
            const int nxt = cur ^ 1;
            *(int4*)&Ks[nxt][krow][kseg] = rk0;
            *(int4*)&Ks[nxt][krow][kseg + 8] = rk1;
            *(int4*)&Vs[nxt][krow][kseg] = rv0;
            *(int4*)&Vs[nxt][krow][kseg + 8] = rv1;
        }
    }

    // epilogue: O /= l.  acc_o C-layout: e = (r&3)+8*(r>>2)+4*hi+32*et, q = lane&31.
    const float il = 1.0f / acc_l[0];
    float* op = attn_out + ((size_t)b * L_ + qrow) * D_ + h * E_ + hi * 4;
#pragma unroll
    for (int et = 0; et < 2; et++)
#pragma unroll
        for (int rg = 0; rg < 4; rg++) {
            float4 ov;
            ov.x = acc_o[et][rg * 4 + 0] * il;
            ov.y = acc_o[et][rg * 4 + 1] * il;
            ov.z = acc_o[et][rg * 4 + 2] * il;
            ov.w = acc_o[et][rg * 4 + 3] * il;
            *(float4*)(op + et * 32 + rg * 8) = ov;
        }
}

// ---------------- residual + layernorm (vectorized), optional second input ----------------
__global__ __launch_bounds__(256) void ln_kernel(const float* __restrict__ A,
                                                 const float* __restrict__ Bres,
                                                 const float* __restrict__ gamma,
                                                 const float* __restrict__ beta,
                                                 float* __restrict__ out_f32,
                                                 bf16* __restrict__ out_bf16) {
    __shared__ float reds[4], reds2[4];
    const int row = blockIdx.x, tid = threadIdx.x;
    const int c4 = tid * 4;
    float4 va = *(const float4*)(A + (size_t)row * D_ + c4);
    if (Bres) {
        float4 vb = *(const float4*)(Bres + (size_t)row * D_ + c4);
        va.x += vb.x; va.y += vb.y; va.z += vb.z; va.w += vb.w;
    }
    float s = va.x + va.y + va.z + va.w;
    float s2 = va.x * va.x + va.y * va.y + va.z * va.z + va.w * va.w;
#pragma unroll
    for (int o = 32; o > 0; o >>= 1) {
        s += __shfl_down(s, o, 64);
        s2 += __shfl_down(s2, o, 64);
    }
    if ((tid & 63) == 0) { reds[tid >> 6] = s; reds2[tid >> 6] = s2; }
    __syncthreads();
    s = reds[0] + reds[1] + reds[2] + reds[3];
    s2 = reds2[0] + reds2[1] + reds2[2] + reds2[3];
    float mean = s * (1.0f / D_);
    float var = s2 * (1.0f / D_) - mean * mean;
    float r = rsqrtf(var + 1e-5f);
    float4 vg = *(const float4*)(gamma + c4);
    float4 vbt = *(const float4*)(beta + c4);
    float4 o;
    o.x = (va.x - mean) * r * vg.x + vbt.x;
    o.y = (va.y - mean) * r * vg.y + vbt.y;
    o.z = (va.z - mean) * r * vg.z + vbt.z;
    o.w = (va.w - mean) * r * vg.w + vbt.w;
    if (out_f32) *(float4*)(out_f32 + (size_t)row * D_ + c4) = o;
    if (out_bf16) {
        unsigned p0 = ((unsigned)(unsigned short)f2bf(o.x)) | (((unsigned)(unsigned short)f2bf(o.y)) << 16);
        unsigned p1 = ((unsigned)(unsigned short)f2bf(o.z)) | (((unsigned)(unsigned short)f2bf(o.w)) << 16);
        int2 pk = make_int2((int)p0, (int)p1);
        *(int2*)((short*)out_bf16 + (size_t)row * D_ + c4) = pk;
    }
}

// ---------------- bf16 MFMA GEMM, B-transposed ----------------
// m97 fragment layout + T3 minimum-2-phase double-buffered pipeline + T1 XCD swizzle.
// Per K-step: barrier (drains prev stage's vmcnt) -> issue next stage -> compute.
// C[M][N] = sum_k A[m][k]*Bw[n][k] (+bias)
// EPI 0: relu -> bf16 out;  EPI 1: fp32 out;  EPI 2: fp32 out + residual RES
template <int EPI>
__global__ __launch_bounds__(256, 4) void gemm_bt(const bf16* __restrict__ A,
                                                  const bf16* __restrict__ Bw,
                                                  const float* __restrict__ bias,
                                                  const float* __restrict__ RES,
                                                  void* __restrict__ Cout,
                                                  int M, int N, int K) {
    __shared__ short As[2][128 * 32];
    __shared__ short Bs[2][128 * 32];
    const int tid = threadIdx.x;

    // T1: bijective XCD-aware swizzle (requires nwg % 8 == 0; holds: 2048 / 512)
    const int nbx = gridDim.x;
    const int id = blockIdx.y * nbx + blockIdx.x;
    const int chunk = (nbx * gridDim.y) >> 3;
    const int swz = (id & 7) * chunk + (id >> 3);
    const int bn = swz % nbx, bm = swz / nbx;

    const int wave = tid >> 6, lane = tid & 63;
    const int wm = (wave >> 1) * 64, wn = (wave & 1) * 64;
    const int lrow = lane & 15, quad = lane >> 4;

    const int cg = (lane & 3) * 8;   // fetch chunk (shorts) — identity layout (m97)
    const int rsub = lane >> 2;      // row within 16-row DMA group

    // per-lane global base: row (bm*128 + wave*32 + rsub), col cg
    const short* Ag = (const short*)A + (size_t)(bm * 128 + wave * 32 + rsub) * K + cg;
    const short* Bg = (const short*)Bw + (size_t)(bn * 128 + wave * 32 + rsub) * K + cg;
    short* AsW0 = &As[0][(wave * 32) * 32];
    short* AsW1 = &As[1][(wave * 32) * 32];
    short* BsW0 = &Bs[0][(wave * 32) * 32];
    short* BsW1 = &Bs[1][(wave * 32) * 32];

#define STAGE_G(asw, bsw, kk)                                  \
    do {                                                       \
        gl_lds16(Ag + (kk), (asw));                            \
        gl_lds16(Ag + (size_t)16 * K + (kk), (asw) + 16 * 32); \
        gl_lds16(Bg + (kk), (bsw));                            \
        gl_lds16(Bg + (size_t)16 * K + (kk), (bsw) + 16 * 32); \
    } while (0)

    f32x4 acc[4][4];
#pragma unroll
    for (int i = 0; i < 4; i++)
#pragma unroll
        for (int j = 0; j < 4; j++) acc[i][j] = (f32x4){0.f, 0.f, 0.f, 0.f};

#define COMPUTE_G(buf)                                                              \
    do {                                                                            \
        short8 af[4], bfg[4];                                                       \
        _Pragma("unroll") for (int i = 0; i < 4; i++)                               \
            af[i] = *(const short8*)&As[buf][(wm + i * 16 + lrow) * 32 + quad * 8]; \
        _Pragma("unroll") for (int j = 0; j < 4; j++)                               \
            bfg[j] = *(const short8*)&Bs[buf][(wn + j * 16 + lrow) * 32 + quad * 8];\
        _Pragma("unroll") for (int i = 0; i < 4; i++)                               \
            _Pragma("unroll") for (int j = 0; j < 4; j++)                           \
                acc[i][j] = __builtin_amdgcn_mfma_f32_16x16x32_bf16(af[i], bfg[j],  \
                                                                    acc[i][j], 0, 0, 0); \
    } while (0)

    // prologue: stage K-tile 0 into buf 0
    STAGE_G(AsW0, BsW0, 0);

    // main loop, manually unrolled x2 for static buffer indices (K % 64 == 0)
    for (int k0 = 0; k0 < K; k0 += 64) {
        __syncthreads();                       // drains vmcnt(0): buf0 ready; buf1 reads done
        if (k0 + 32 < K) STAGE_G(AsW1, BsW1, k0 + 32);
        COMPUTE_G(0);
        __syncthreads();                       // drains vmcnt(0): buf1 ready; buf0 reads done
        if (k0 + 64 < K) STAGE_G(AsW0, BsW0, k0 + 64);
        COMPUTE_G(1);
    }
#undef STAGE_G
#undef COMPUTE_G

#pragma unroll
    for (int i = 0; i < 4; i++) {
#pragma unroll
        for (int j = 0; j < 4; j++) {
            int col = bn * 128 + wn + j * 16 + lrow;
            float bv = bias[col];
#pragma unroll
            for (int r = 0; r < 4; r++) {
                int row = bm * 128 + wm + i * 16 + quad * 4 + r;
                float v = acc[i][j][r] + bv;
                if (EPI == 0) {
                    v = fmaxf(v, 0.f);
                    ((bf16*)Cout)[(size_t)row * N + col] = __float2bfloat16(v);
                } else if (EPI == 1) {
                    ((float*)Cout)[(size_t)row * N + col] = v;
                } else {
                    v += RES[(size_t)row * N + col];
                    ((float*)Cout)[(size_t)row * N + col] = v;
                }
            }
        }
    }
}

// ---------------- launch ----------------
extern "C" void kernel_launch(void* const* d_in, const int* in_sizes, int n_in,
                              void* d_out, int out_size, void* d_ws, size_t ws_size,
                              hipStream_t stream) {
    const float* x = (const float*)d_in[0];
    const float* w1 = (const float*)d_in[1];
    const float* b1 = (const float*)d_in[2];
    const float* w2 = (const float*)d_in[3];
    const float* b2 = (const float*)d_in[4];
    const float* g1 = (const float*)d_in[5];
    const float* be1 = (const float*)d_in[6];
    const float* g2 = (const float*)d_in[7];
    const float* be2 = (const float*)d_in[8];
    float* out = (float*)d_out;

    char* ws = (char*)d_ws;
    const size_t MB = 1024 * 1024;
    float* attn_out = (float*)(ws);            // 32 MiB
    float* x1 = (float*)(ws + 32 * MB);        // 32 MiB
    bf16* x1b = (bf16*)(ws + 64 * MB);         // 16 MiB
    bf16* w1b = (bf16*)(ws + 80 * MB);         // 8 MiB
    bf16* w2b = (bf16*)(ws + 88 * MB);         // 8 MiB
    bf16* hb = (bf16*)(ws + 96 * MB);          // 64 MiB (GEMM phase)
    // attention-phase buffers alias hb's region (dead once gemm1 runs):
    short* xb = (short*)(ws + 96 * MB);        // 16 MiB bf16 x
    short* vt = (short*)(ws + 112 * MB);       // 16 MiB bf16 x^T per (b,h)
    float* y2 = attn_out;                      // reuse

    convert_bf16_kernel<<<4096, 256, 0, stream>>>(w1, w1b, F_ * D_);
    convert_bf16_kernel<<<4096, 256, 0, stream>>>(w2, w2b, D_ * F_);
    transpose_vt_kernel<<<dim3(B_ * H_, L_ / 64), 256, 0, stream>>>(x, vt, xb);

    flash_attn_kernel<<<B_ * H_ * (L_ / 128), 256, 0, stream>>>(x, xb, vt, attn_out);

    ln_kernel<<<B_ * L_, 256, 0, stream>>>(x, attn_out, g1, be1, x1, x1b);

    gemm_bt<0><<<dim3(F_ / 128, (B_ * L_) / 128), 256, 0, stream>>>(
        x1b, w1b, b1, nullptr, (void*)hb, B_ * L_, F_, D_);
    gemm_bt<2><<<dim3(D_ / 128, (B_ * L_) / 128), 256, 0, stream>>>(
        hb, w2b, b2, x1, (void*)y2, B_ * L_, D_, F_);

    ln_kernel<<<B_ * L_, 256, 0, stream>>>(y2, nullptr, g2, be2, out, nullptr);
}

// Round 4
// 296.220 us; speedup vs baseline: 1.0613x; 1.0613x over previous
//
#include <hip/hip_runtime.h>
#include <hip/hip_bf16.h>

#define B_ 4
#define L_ 2048
#define D_ 1024
#define F_ 4096
#define H_ 16
#define E_ 64

typedef __hip_bfloat16 bf16;
typedef __attribute__((ext_vector_type(8))) short short8;
typedef __attribute__((ext_vector_type(4))) float f32x4;
typedef __attribute__((ext_vector_type(16))) float f32x16;

__device__ __forceinline__ short f2bf(float f) {
    union { float f; unsigned u; } v;
    v.f = f;
    unsigned r = (v.u + 0x7fff + ((v.u >> 16) & 1)) >> 16;
    return (short)r;
}

// async global->LDS, 16B per lane, lands at ldsbase + lane*16
__device__ __forceinline__ void gl_lds16(const short* g, short* l) {
    __builtin_amdgcn_global_load_lds((const __attribute__((address_space(1))) void*)g,
                                     (__attribute__((address_space(3))) void*)l, 16, 0, 0);
}

// ---------------- fp32 -> bf16 convert ----------------
__global__ __launch_bounds__(256) void convert_bf16_kernel(const float* __restrict__ src,
                                                           bf16* __restrict__ dst, int n) {
    int i = (blockIdx.x * 256 + threadIdx.x) * 4;
    if (i + 3 < n) {
        float4 v = *(const float4*)(src + i);
        dst[i + 0] = __float2bfloat16(v.x);
        dst[i + 1] = __float2bfloat16(v.y);
        dst[i + 2] = __float2bfloat16(v.z);
        dst[i + 3] = __float2bfloat16(v.w);
    }
}

// ---------------- V^T pre-pass + bf16 x copy ----------------
__global__ __launch_bounds__(256) void transpose_vt_kernel(const float* __restrict__ x,
                                                           short* __restrict__ vt,
                                                           short* __restrict__ xb) {
    __shared__ float tile[64][65];
    const int bh = blockIdx.x, lt = blockIdx.y;
    const int b = bh >> 4, h = bh & 15;
    const int l0 = lt * 64;
    for (int idx = threadIdx.x; idx < 4096; idx += 256) {
        int r = idx >> 6, c = idx & 63;
        float v = x[((size_t)b * L_ + l0 + r) * D_ + h * E_ + c];
        tile[r][c] = v;
        xb[((size_t)b * L_ + l0 + r) * D_ + h * E_ + c] = f2bf(v);
    }
    __syncthreads();
    for (int idx = threadIdx.x; idx < 4096; idx += 256) {
        int e = idx >> 6, l = idx & 63;
        vt[((size_t)bh * E_ + e) * L_ + l0 + l] = f2bf(tile[l][e]);
    }
}

// ---------------- flash attention, swapped-operand 32x32 MFMA, in-register P ----------------
__global__ __launch_bounds__(256, 3) void flash_attn_kernel(const float* __restrict__ x,
                                                            const short* __restrict__ xb,
                                                            const short* __restrict__ vt,
                                                            float* __restrict__ attn_out) {
    __shared__ short Ks[2][64][72];   // [buf][s][e]
    __shared__ short Vs[2][64][72];   // [buf][e][s]

    const int tid = threadIdx.x;
    const int w = tid >> 6, lane = tid & 63;
    const int l31 = lane & 31;
    const int hi = lane >> 5;
    const int hi8 = hi * 8;
    const int qt = blockIdx.x & 15;
    const int bh = blockIdx.x >> 4;
    const int b = bh >> 4, h = bh & 15;
    const int q0 = qt * 128;

    const short* kbase = xb + (size_t)b * L_ * D_ + h * E_;

    const float QS = 0.125f * 1.44269504f;
    const int qrow = q0 + w * 32 + l31;
    short8 qf[4];
    {
        const float* qp = x + ((size_t)b * L_ + qrow) * D_ + h * E_;
#pragma unroll
        for (int ks = 0; ks < 4; ks++) {
            float4 v0 = *(const float4*)(qp + ks * 16 + hi8);
            float4 v1 = *(const float4*)(qp + ks * 16 + hi8 + 4);
            short8 sc;
            sc[0] = f2bf(v0.x * QS); sc[1] = f2bf(v0.y * QS);
            sc[2] = f2bf(v0.z * QS); sc[3] = f2bf(v0.w * QS);
            sc[4] = f2bf(v1.x * QS); sc[5] = f2bf(v1.y * QS);
            sc[6] = f2bf(v1.z * QS); sc[7] = f2bf(v1.w * QS);
            qf[ks] = sc;
        }
    }

    short8 ones;
#pragma unroll
    for (int z = 0; z < 8; z++) ones[z] = (short)0x3F80;

    f32x16 acc_o[2];
    f32x16 acc_l;
#pragma unroll
    for (int r = 0; r < 16; r++) { acc_o[0][r] = 0.f; acc_o[1][r] = 0.f; acc_l[r] = 0.f; }

    const int krow = tid >> 2, kseg = (tid & 3) * 16;

    int4 rk0, rk1, rv0, rv1;
    {
        const short* ks = kbase + (size_t)krow * D_ + kseg;
        rk0 = *(const int4*)ks;
        rk1 = *(const int4*)(ks + 8);
        const short* vs = vt + ((size_t)bh * E_ + krow) * L_ + kseg;
        rv0 = *(const int4*)vs;
        rv1 = *(const int4*)(vs + 8);
    }
    *(int4*)&Ks[0][krow][kseg] = rk0;
    *(int4*)&Ks[0][krow][kseg + 8] = rk1;
    *(int4*)&Vs[0][krow][kseg] = rv0;
    *(int4*)&Vs[0][krow][kseg + 8] = rv1;

    for (int t = 0; t < L_ / 64; t++) {
        const int cur = t & 1;
        __syncthreads();

        if (t + 1 < L_ / 64) {
            const short* ks = kbase + (size_t)((t + 1) * 64 + krow) * D_ + kseg;
            rk0 = *(const int4*)ks;
            rk1 = *(const int4*)(ks + 8);
            const short* vs = vt + ((size_t)bh * E_ + krow) * L_ + (t + 1) * 64 + kseg;
            rv0 = *(const int4*)vs;
            rv1 = *(const int4*)(vs + 8);
        }

        f32x16 accp0, accp1;
#pragma unroll
        for (int r = 0; r < 16; r++) { accp0[r] = 0.f; accp1[r] = 0.f; }
        __builtin_amdgcn_s_setprio(1);
#pragma unroll
        for (int ks = 0; ks < 4; ks++) {
            short8 kf0 = *(const short8*)&Ks[cur][l31][ks * 16 + hi8];
            short8 kf1 = *(const short8*)&Ks[cur][32 + l31][ks * 16 + hi8];
            accp0 = __builtin_amdgcn_mfma_f32_32x32x16_bf16(kf0, qf[ks], accp0, 0, 0, 0);
            accp1 = __builtin_amdgcn_mfma_f32_32x32x16_bf16(kf1, qf[ks], accp1, 0, 0, 0);
        }
        __builtin_amdgcn_s_setprio(0);

        float pe[2][16];
#pragma unroll
        for (int r = 0; r < 16; r++) {
            pe[0][r] = __builtin_amdgcn_exp2f(accp0[r]);
            pe[1][r] = __builtin_amdgcn_exp2f(accp1[r]);
        }

#pragma unroll
        for (int k2 = 0; k2 < 4; k2++) {
            const int tt = k2 >> 1, o = (k2 & 1) * 8;
            unsigned X0, X1, Y0, Y1;
            asm("v_cvt_pk_bf16_f32 %0, %1, %2" : "=v"(X0) : "v"(pe[tt][o + 0]), "v"(pe[tt][o + 1]));
            asm("v_cvt_pk_bf16_f32 %0, %1, %2" : "=v"(X1) : "v"(pe[tt][o + 2]), "v"(pe[tt][o + 3]));
            asm("v_cvt_pk_bf16_f32 %0, %1, %2" : "=v"(Y0) : "v"(pe[tt][o + 4]), "v"(pe[tt][o + 5]));
            asm("v_cvt_pk_bf16_f32 %0, %1, %2" : "=v"(Y1) : "v"(pe[tt][o + 6]), "v"(pe[tt][o + 7]));
            unsigned sx0 = (unsigned)__shfl_xor((int)X0, 32, 64);
            unsigned sx1 = (unsigned)__shfl_xor((int)X1, 32, 64);
            unsigned sy0 = (unsigned)__shfl_xor((int)Y0, 32, 64);
            unsigned sy1 = (unsigned)__shfl_xor((int)Y1, 32, 64);
            unsigned w0 = hi ? sy0 : X0;
            unsigned w1 = hi ? sy1 : X1;
            unsigned w2 = hi ? Y0 : sx0;
            unsigned w3 = hi ? Y1 : sx1;
            int4 wi = make_int4((int)w0, (int)w1, (int)w2, (int)w3);
            short8 pb = *(short8*)&wi;

            __builtin_amdgcn_s_setprio(1);
            acc_l = __builtin_amdgcn_mfma_f32_32x32x16_bf16(ones, pb, acc_l, 0, 0, 0);
            short8 vf0 = *(const short8*)&Vs[cur][l31][k2 * 16 + hi8];
            short8 vf1 = *(const short8*)&Vs[cur][32 + l31][k2 * 16 + hi8];
            acc_o[0] = __builtin_amdgcn_mfma_f32_32x32x16_bf16(vf0, pb, acc_o[0], 0, 0, 0);
            acc_o[1] = __builtin_amdgcn_mfma_f32_32x32x16_bf16(vf1, pb, acc_o[1], 0, 0, 0);
            __builtin_amdgcn_s_setprio(0);
        }

        if (t + 1 < L_ / 64) {
            const int nxt = cur ^ 1;
            *(int4*)&Ks[nxt][krow][kseg] = rk0;
            *(int4*)&Ks[nxt][krow][kseg + 8] = rk1;
            *(int4*)&Vs[nxt][krow][kseg] = rv0;
            *(int4*)&Vs[nxt][krow][kseg + 8] = rv1;
        }
    }

    const float il = 1.0f / acc_l[0];
    float* op = attn_out + ((size_t)b * L_ + qrow) * D_ + h * E_ + hi * 4;
#pragma unroll
    for (int et = 0; et < 2; et++)
#pragma unroll
        for (int rg = 0; rg < 4; rg++) {
            float4 ov;
            ov.x = acc_o[et][rg * 4 + 0] * il;
            ov.y = acc_o[et][rg * 4 + 1] * il;
            ov.z = acc_o[et][rg * 4 + 2] * il;
            ov.w = acc_o[et][rg * 4 + 3] * il;
            *(float4*)(op + et * 32 + rg * 8) = ov;
        }
}

// ---------------- residual + layernorm (vectorized), optional second input ----------------
__global__ __launch_bounds__(256) void ln_kernel(const float* __restrict__ A,
                                                 const float* __restrict__ Bres,
                                                 const float* __restrict__ gamma,
                                                 const float* __restrict__ beta,
                                                 float* __restrict__ out_f32,
                                                 bf16* __restrict__ out_bf16) {
    __shared__ float reds[4], reds2[4];
    const int row = blockIdx.x, tid = threadIdx.x;
    const int c4 = tid * 4;
    float4 va = *(const float4*)(A + (size_t)row * D_ + c4);
    if (Bres) {
        float4 vb = *(const float4*)(Bres + (size_t)row * D_ + c4);
        va.x += vb.x; va.y += vb.y; va.z += vb.z; va.w += vb.w;
    }
    float s = va.x + va.y + va.z + va.w;
    float s2 = va.x * va.x + va.y * va.y + va.z * va.z + va.w * va.w;
#pragma unroll
    for (int o = 32; o > 0; o >>= 1) {
        s += __shfl_down(s, o, 64);
        s2 += __shfl_down(s2, o, 64);
    }
    if ((tid & 63) == 0) { reds[tid >> 6] = s; reds2[tid >> 6] = s2; }
    __syncthreads();
    s = reds[0] + reds[1] + reds[2] + reds[3];
    s2 = reds2[0] + reds2[1] + reds2[2] + reds2[3];
    float mean = s * (1.0f / D_);
    float var = s2 * (1.0f / D_) - mean * mean;
    float r = rsqrtf(var + 1e-5f);
    float4 vg = *(const float4*)(gamma + c4);
    float4 vbt = *(const float4*)(beta + c4);
    float4 o;
    o.x = (va.x - mean) * r * vg.x + vbt.x;
    o.y = (va.y - mean) * r * vg.y + vbt.y;
    o.z = (va.z - mean) * r * vg.z + vbt.z;
    o.w = (va.w - mean) * r * vg.w + vbt.w;
    if (out_f32) *(float4*)(out_f32 + (size_t)row * D_ + c4) = o;
    if (out_bf16) {
        unsigned p0 = ((unsigned)(unsigned short)f2bf(o.x)) | (((unsigned)(unsigned short)f2bf(o.y)) << 16);
        unsigned p1 = ((unsigned)(unsigned short)f2bf(o.z)) | (((unsigned)(unsigned short)f2bf(o.w)) << 16);
        int2 pk = make_int2((int)p0, (int)p1);
        *(int2*)((short*)out_bf16 + (size_t)row * D_ + c4) = pk;
    }
}

// ---------------- bf16 MFMA GEMM, 256-row tile, 8-wave deep-pipelined (T2+T3+T4+T5) ----------------
// BM=256, BN in {256,128}, BK=64, 512 thr = 8 waves (2M x 4N). Double-buffered LDS.
// Per K-tile: 4 phases {ds_read quadrant frags | stage -> lgkmcnt(0) -> setprio+MFMA -> s_barrier}.
// All of K-tile t+1 staged during t's ph0/ph1; single vmcnt(0) at top of iteration
// (issue-to-drain distance = ~4 phases of compute, so the drain is covered).
// T2 swizzle: physical 16B chunk q' = q ^ (row&7), applied on BOTH stage-source and ds_read.
// C[M][N] = sum_k A[m][k]*Bw[n][k] (+bias). EPI 0: relu->bf16; EPI 2: fp32 + residual.
template <int EPI, int BN>
__global__ __launch_bounds__(512, 2) void gemm8p(const bf16* __restrict__ A,
                                                 const bf16* __restrict__ Bw,
                                                 const float* __restrict__ bias,
                                                 const float* __restrict__ RES,
                                                 void* __restrict__ Cout,
                                                 int M, int N, int K) {
    constexpr int WN = BN / 4;        // per-wave col span (64 or 32)
    constexpr int JF = WN / 32;       // B frags per quadrant (2 or 1)
    constexpr int BISS = BN / 64;     // B stage issues per K-tile (4 or 2)
    __shared__ short As[2][256 * 64];
    __shared__ short Bs[2][BN * 64];

    const int tid = threadIdx.x;
    const int wid = tid >> 6, lane = tid & 63;
    const int wr = wid >> 2, wc = wid & 3;
    const int lrow = lane & 15, quad = lane >> 4;

    // T1: bijective XCD swizzle (grid % 8 == 0 for both instantiations)
    const int nbx = gridDim.x;
    const int id = blockIdx.y * nbx + blockIdx.x;
    const int chunk = (nbx * gridDim.y) >> 3;
    const int swz = (id & 7) * chunk + (id >> 3);
    const int bn = swz % nbx, bm = swz / nbx;

    // staging: lane covers row (wid*8 + lane>>3) of each 64-row issue block;
    // source chunk pre-permuted so linear LDS dest holds swizzled layout (rule 21)
    const int srow = wid * 8 + (lane >> 3);
    const int scol = ((lane & 7) ^ ((lane >> 3) & 7)) * 8;
    const short* Ag = (const short*)A + (size_t)(bm * 256 + srow) * K + scol;
    const short* Bg = (const short*)Bw + (size_t)(bn * BN + srow) * K + scol;

    f32x4 acc[2][2][4][JF];
#pragma unroll
    for (int qr = 0; qr < 2; qr++)
#pragma unroll
        for (int qc = 0; qc < 2; qc++)
#pragma unroll
            for (int i = 0; i < 4; i++)
#pragma unroll
                for (int j = 0; j < JF; j++) acc[qr][qc][i][j] = (f32x4){0.f, 0.f, 0.f, 0.f};

#define STAGE_A(b, k0)                                                              \
    do {                                                                            \
        _Pragma("unroll") for (int s = 0; s < 4; s++)                               \
            gl_lds16(Ag + (size_t)s * 64 * K + (k0), &As[b][(s * 64 + wid * 8) * 64]); \
    } while (0)
#define STAGE_B(b, k0)                                                              \
    do {                                                                            \
        _Pragma("unroll") for (int s = 0; s < BISS; s++)                            \
            gl_lds16(Bg + (size_t)s * 64 * K + (k0), &Bs[b][(s * 64 + wid * 8) * 64]); \
    } while (0)

    // swizzled ds_read of one 8-bf16 fragment chunk
#define RD_A(b, R, q) (*(const short8*)&As[b][(R) * 64 + (((q) ^ ((R) & 7)) * 8)])
#define RD_B(b, R, q) (*(const short8*)&Bs[b][(R) * 64 + (((q) ^ ((R) & 7)) * 8)])
#define LGKM0()                                          \
    do {                                                 \
        asm volatile("s_waitcnt lgkmcnt(0)" ::: "memory"); \
        __builtin_amdgcn_sched_barrier(0);               \
    } while (0)

    // prologue: stage K-tile 0 -> buf 0
    STAGE_A(0, 0);
    STAGE_B(0, 0);

    const int NT = K / 64;
    for (int t = 0; t < NT; t++) {
        const int p = t & 1;
        asm volatile("s_waitcnt vmcnt(0)" ::: "memory");   // own K-tile-t loads landed
        __builtin_amdgcn_s_barrier();                       // all waves' loads landed / reads done
        __builtin_amdgcn_sched_barrier(0);
        const int kn = (t + 1) * 64;
        const bool more = t + 1 < NT;

        short8 afr[4][2], bfr[JF][2];

        // ---- ph0: quadrant (0,0); stage A(t+1) ----
#pragma unroll
        for (int i = 0; i < 4; i++)
#pragma unroll
            for (int kq = 0; kq < 2; kq++)
                afr[i][kq] = RD_A(p, wr * 128 + i * 16 + lrow, kq * 4 + quad);
#pragma unroll
        for (int j = 0; j < JF; j++)
#pragma unroll
            for (int kq = 0; kq < 2; kq++)
                bfr[j][kq] = RD_B(p, wc * WN + j * 16 + lrow, kq * 4 + quad);
        if (more) STAGE_A(p ^ 1, kn);
        LGKM0();
        __builtin_amdgcn_s_setprio(1);
#pragma unroll
        for (int i = 0; i < 4; i++)
#pragma unroll
            for (int j = 0; j < JF; j++)
#pragma unroll
                for (int kq = 0; kq < 2; kq++)
                    acc[0][0][i][j] = __builtin_amdgcn_mfma_f32_16x16x32_bf16(
                        afr[i][kq], bfr[j][kq], acc[0][0][i][j], 0, 0, 0);
        __builtin_amdgcn_s_setprio(0);
        __builtin_amdgcn_s_barrier();

        // ---- ph1: quadrant (0,1); stage B(t+1) ----
#pragma unroll
        for (int j = 0; j < JF; j++)
#pragma unroll
            for (int kq = 0; kq < 2; kq++)
                bfr[j][kq] = RD_B(p, wc * WN + WN / 2 + j * 16 + lrow, kq * 4 + quad);
        if (more) STAGE_B(p ^ 1, kn);
        LGKM0();
        __builtin_amdgcn_s_setprio(1);
#pragma unroll
        for (int i = 0; i < 4; i++)
#pragma unroll
            for (int j = 0; j < JF; j++)
#pragma unroll
                for (int kq = 0; kq < 2; kq++)
                    acc[0][1][i][j] = __builtin_amdgcn_mfma_f32_16x16x32_bf16(
                        afr[i][kq], bfr[j][kq], acc[0][1][i][j], 0, 0, 0);
        __builtin_amdgcn_s_setprio(0);
        __builtin_amdgcn_s_barrier();

        // ---- ph2: quadrant (1,1); re-read A half 1 ----
#pragma unroll
        for (int i = 0; i < 4; i++)
#pragma unroll
            for (int kq = 0; kq < 2; kq++)
                afr[i][kq] = RD_A(p, wr * 128 + 64 + i * 16 + lrow, kq * 4 + quad);
        LGKM0();
        __builtin_amdgcn_s_setprio(1);
#pragma unroll
        for (int i = 0; i < 4; i++)
#pragma unroll
            for (int j = 0; j < JF; j++)
#pragma unroll
                for (int kq = 0; kq < 2; kq++)
                    acc[1][1][i][j] = __builtin_amdgcn_mfma_f32_16x16x32_bf16(
                        afr[i][kq], bfr[j][kq], acc[1][1][i][j], 0, 0, 0);
        __builtin_amdgcn_s_setprio(0);
        __builtin_amdgcn_s_barrier();

        // ---- ph3: quadrant (1,0); re-read B qc=0 ----
#pragma unroll
        for (int j = 0; j < JF; j++)
#pragma unroll
            for (int kq = 0; kq < 2; kq++)
                bfr[j][kq] = RD_B(p, wc * WN + j * 16 + lrow, kq * 4 + quad);
        LGKM0();
        __builtin_amdgcn_s_setprio(1);
#pragma unroll
        for (int i = 0; i < 4; i++)
#pragma unroll
            for (int j = 0; j < JF; j++)
#pragma unroll
                for (int kq = 0; kq < 2; kq++)
                    acc[1][0][i][j] = __builtin_amdgcn_mfma_f32_16x16x32_bf16(
                        afr[i][kq], bfr[j][kq], acc[1][0][i][j], 0, 0, 0);
        __builtin_amdgcn_s_setprio(0);
        // (phase-3 barrier merged with top-of-loop barrier)
    }
#undef STAGE_A
#undef STAGE_B
#undef RD_A
#undef RD_B
#undef LGKM0

    // epilogue
#pragma unroll
    for (int qr = 0; qr < 2; qr++)
#pragma unroll
        for (int qc = 0; qc < 2; qc++)
#pragma unroll
            for (int i = 0; i < 4; i++)
#pragma unroll
                for (int j = 0; j < JF; j++) {
                    int col = bn * BN + wc * WN + qc * (WN / 2) + j * 16 + lrow;
                    float bv = bias[col];
#pragma unroll
                    for (int r = 0; r < 4; r++) {
                        int row = bm * 256 + wr * 128 + qr * 64 + i * 16 + quad * 4 + r;
                        float v = acc[qr][qc][i][j][r] + bv;
                        if (EPI == 0) {
                            v = fmaxf(v, 0.f);
                            ((bf16*)Cout)[(size_t)row * N + col] = __float2bfloat16(v);
                        } else if (EPI == 1) {
                            ((float*)Cout)[(size_t)row * N + col] = v;
                        } else {
                            v += RES[(size_t)row * N + col];
                            ((float*)Cout)[(size_t)row * N + col] = v;
                        }
                    }
                }
}

// ---------------- launch ----------------
extern "C" void kernel_launch(void* const* d_in, const int* in_sizes, int n_in,
                              void* d_out, int out_size, void* d_ws, size_t ws_size,
                              hipStream_t stream) {
    const float* x = (const float*)d_in[0];
    const float* w1 = (const float*)d_in[1];
    const float* b1 = (const float*)d_in[2];
    const float* w2 = (const float*)d_in[3];
    const float* b2 = (const float*)d_in[4];
    const float* g1 = (const float*)d_in[5];
    const float* be1 = (const float*)d_in[6];
    const float* g2 = (const float*)d_in[7];
    const float* be2 = (const float*)d_in[8];
    float* out = (float*)d_out;

    char* ws = (char*)d_ws;
    const size_t MB = 1024 * 1024;
    float* attn_out = (float*)(ws);            // 32 MiB
    float* x1 = (float*)(ws + 32 * MB);        // 32 MiB
    bf16* x1b = (bf16*)(ws + 64 * MB);         // 16 MiB
    bf16* w1b = (bf16*)(ws + 80 * MB);         // 8 MiB
    bf16* w2b = (bf16*)(ws + 88 * MB);         // 8 MiB
    bf16* hb = (bf16*)(ws + 96 * MB);          // 64 MiB (GEMM phase)
    // attention-phase buffers alias hb's region (dead once gemm1 runs):
    short* xb = (short*)(ws + 96 * MB);        // 16 MiB bf16 x
    short* vt = (short*)(ws + 112 * MB);       // 16 MiB bf16 x^T per (b,h)
    float* y2 = attn_out;                      // reuse

    convert_bf16_kernel<<<4096, 256, 0, stream>>>(w1, w1b, F_ * D_);
    convert_bf16_kernel<<<4096, 256, 0, stream>>>(w2, w2b, D_ * F_);
    transpose_vt_kernel<<<dim3(B_ * H_, L_ / 64), 256, 0, stream>>>(x, vt, xb);

    flash_attn_kernel<<<B_ * H_ * (L_ / 128), 256, 0, stream>>>(x, xb, vt, attn_out);

    ln_kernel<<<B_ * L_, 256, 0, stream>>>(x, attn_out, g1, be1, x1, x1b);

    // gemm1: M=8192, N=4096, K=1024 -> grid 16 x 32 = 512 wg
    gemm8p<0, 256><<<dim3(F_ / 256, (B_ * L_) / 256), 512, 0, stream>>>(
        x1b, w1b, b1, nullptr, (void*)hb, B_ * L_, F_, D_);
    // gemm2: M=8192, N=1024, K=4096 -> BN=128 -> grid 8 x 32 = 256 wg (1/CU)
    gemm8p<2, 128><<<dim3(D_ / 128, (B_ * L_) / 256), 512, 0, stream>>>(
        hb, w2b, b2, x1, (void*)y2, B_ * L_, D_, F_);

    ln_kernel<<<B_ * L_, 256, 0, stream>>>(y2, nullptr, g2, be2, out, nullptr);
}

// Round 5
// 274.877 us; speedup vs baseline: 1.1437x; 1.0776x over previous
//
#include <hip/hip_runtime.h>
#include <hip/hip_bf16.h>

#define B_ 4
#define L_ 2048
#define D_ 1024
#define F_ 4096
#define H_ 16
#define E_ 64

typedef __hip_bfloat16 bf16;
typedef __attribute__((ext_vector_type(8))) short short8;
typedef __attribute__((ext_vector_type(4))) float f32x4;
typedef __attribute__((ext_vector_type(16))) float f32x16;

__device__ __forceinline__ short f2bf(float f) {
    union { float f; unsigned u; } v;
    v.f = f;
    unsigned r = (v.u + 0x7fff + ((v.u >> 16) & 1)) >> 16;
    return (short)r;
}

// async global->LDS, 16B per lane, lands at ldsbase + lane*16
__device__ __forceinline__ void gl_lds16(const short* g, short* l) {
    __builtin_amdgcn_global_load_lds((const __attribute__((address_space(1))) void*)g,
                                     (__attribute__((address_space(3))) void*)l, 16, 0, 0);
}

// ---------------- fp32 -> bf16 convert ----------------
__global__ __launch_bounds__(256) void convert_bf16_kernel(const float* __restrict__ src,
                                                           bf16* __restrict__ dst, int n) {
    int i = (blockIdx.x * 256 + threadIdx.x) * 4;
    if (i + 3 < n) {
        float4 v = *(const float4*)(src + i);
        dst[i + 0] = __float2bfloat16(v.x);
        dst[i + 1] = __float2bfloat16(v.y);
        dst[i + 2] = __float2bfloat16(v.z);
        dst[i + 3] = __float2bfloat16(v.w);
    }
}

// ---------------- V^T pre-pass + bf16 x copy ----------------
__global__ __launch_bounds__(256) void transpose_vt_kernel(const float* __restrict__ x,
                                                           short* __restrict__ vt,
                                                           short* __restrict__ xb) {
    __shared__ float tile[64][65];
    const int bh = blockIdx.x, lt = blockIdx.y;
    const int b = bh >> 4, h = bh & 15;
    const int l0 = lt * 64;
    for (int idx = threadIdx.x; idx < 4096; idx += 256) {
        int r = idx >> 6, c = idx & 63;
        float v = x[((size_t)b * L_ + l0 + r) * D_ + h * E_ + c];
        tile[r][c] = v;
        xb[((size_t)b * L_ + l0 + r) * D_ + h * E_ + c] = f2bf(v);
    }
    __syncthreads();
    for (int idx = threadIdx.x; idx < 4096; idx += 256) {
        int e = idx >> 6, l = idx & 63;
        vt[((size_t)bh * E_ + e) * L_ + l0 + l] = f2bf(tile[l][e]);
    }
}

// ---------------- flash attention, swapped-operand 32x32 MFMA, in-register P ----------------
__global__ __launch_bounds__(256, 3) void flash_attn_kernel(const float* __restrict__ x,
                                                            const short* __restrict__ xb,
                                                            const short* __restrict__ vt,
                                                            float* __restrict__ attn_out) {
    __shared__ short Ks[2][64][72];   // [buf][s][e]
    __shared__ short Vs[2][64][72];   // [buf][e][s]

    const int tid = threadIdx.x;
    const int w = tid >> 6, lane = tid & 63;
    const int l31 = lane & 31;
    const int hi = lane >> 5;
    const int hi8 = hi * 8;
    const int qt = blockIdx.x & 15;
    const int bh = blockIdx.x >> 4;
    const int b = bh >> 4, h = bh & 15;
    const int q0 = qt * 128;

    const short* kbase = xb + (size_t)b * L_ * D_ + h * E_;

    const float QS = 0.125f * 1.44269504f;
    const int qrow = q0 + w * 32 + l31;
    short8 qf[4];
    {
        const float* qp = x + ((size_t)b * L_ + qrow) * D_ + h * E_;
#pragma unroll
        for (int ks = 0; ks < 4; ks++) {
            float4 v0 = *(const float4*)(qp + ks * 16 + hi8);
            float4 v1 = *(const float4*)(qp + ks * 16 + hi8 + 4);
            short8 sc;
            sc[0] = f2bf(v0.x * QS); sc[1] = f2bf(v0.y * QS);
            sc[2] = f2bf(v0.z * QS); sc[3] = f2bf(v0.w * QS);
            sc[4] = f2bf(v1.x * QS); sc[5] = f2bf(v1.y * QS);
            sc[6] = f2bf(v1.z * QS); sc[7] = f2bf(v1.w * QS);
            qf[ks] = sc;
        }
    }

    short8 ones;
#pragma unroll
    for (int z = 0; z < 8; z++) ones[z] = (short)0x3F80;

    f32x16 acc_o[2];
    f32x16 acc_l;
#pragma unroll
    for (int r = 0; r < 16; r++) { acc_o[0][r] = 0.f; acc_o[1][r] = 0.f; acc_l[r] = 0.f; }

    const int krow = tid >> 2, kseg = (tid & 3) * 16;

    int4 rk0, rk1, rv0, rv1;
    {
        const short* ks = kbase + (size_t)krow * D_ + kseg;
        rk0 = *(const int4*)ks;
        rk1 = *(const int4*)(ks + 8);
        const short* vs = vt + ((size_t)bh * E_ + krow) * L_ + kseg;
        rv0 = *(const int4*)vs;
        rv1 = *(const int4*)(vs + 8);
    }
    *(int4*)&Ks[0][krow][kseg] = rk0;
    *(int4*)&Ks[0][krow][kseg + 8] = rk1;
    *(int4*)&Vs[0][krow][kseg] = rv0;
    *(int4*)&Vs[0][krow][kseg + 8] = rv1;

    for (int t = 0; t < L_ / 64; t++) {
        const int cur = t & 1;
        __syncthreads();

        if (t + 1 < L_ / 64) {
            const short* ks = kbase + (size_t)((t + 1) * 64 + krow) * D_ + kseg;
            rk0 = *(const int4*)ks;
            rk1 = *(const int4*)(ks + 8);
            const short* vs = vt + ((size_t)bh * E_ + krow) * L_ + (t + 1) * 64 + kseg;
            rv0 = *(const int4*)vs;
            rv1 = *(const int4*)(vs + 8);
        }

        f32x16 accp0, accp1;
#pragma unroll
        for (int r = 0; r < 16; r++) { accp0[r] = 0.f; accp1[r] = 0.f; }
        __builtin_amdgcn_s_setprio(1);
#pragma unroll
        for (int ks = 0; ks < 4; ks++) {
            short8 kf0 = *(const short8*)&Ks[cur][l31][ks * 16 + hi8];
            short8 kf1 = *(const short8*)&Ks[cur][32 + l31][ks * 16 + hi8];
            accp0 = __builtin_amdgcn_mfma_f32_32x32x16_bf16(kf0, qf[ks], accp0, 0, 0, 0);
            accp1 = __builtin_amdgcn_mfma_f32_32x32x16_bf16(kf1, qf[ks], accp1, 0, 0, 0);
        }
        __builtin_amdgcn_s_setprio(0);

        float pe[2][16];
#pragma unroll
        for (int r = 0; r < 16; r++) {
            pe[0][r] = __builtin_amdgcn_exp2f(accp0[r]);
            pe[1][r] = __builtin_amdgcn_exp2f(accp1[r]);
        }

#pragma unroll
        for (int k2 = 0; k2 < 4; k2++) {
            const int tt = k2 >> 1, o = (k2 & 1) * 8;
            unsigned X0, X1, Y0, Y1;
            asm("v_cvt_pk_bf16_f32 %0, %1, %2" : "=v"(X0) : "v"(pe[tt][o + 0]), "v"(pe[tt][o + 1]));
            asm("v_cvt_pk_bf16_f32 %0, %1, %2" : "=v"(X1) : "v"(pe[tt][o + 2]), "v"(pe[tt][o + 3]));
            asm("v_cvt_pk_bf16_f32 %0, %1, %2" : "=v"(Y0) : "v"(pe[tt][o + 4]), "v"(pe[tt][o + 5]));
            asm("v_cvt_pk_bf16_f32 %0, %1, %2" : "=v"(Y1) : "v"(pe[tt][o + 6]), "v"(pe[tt][o + 7]));
            unsigned sx0 = (unsigned)__shfl_xor((int)X0, 32, 64);
            unsigned sx1 = (unsigned)__shfl_xor((int)X1, 32, 64);
            unsigned sy0 = (unsigned)__shfl_xor((int)Y0, 32, 64);
            unsigned sy1 = (unsigned)__shfl_xor((int)Y1, 32, 64);
            unsigned w0 = hi ? sy0 : X0;
            unsigned w1 = hi ? sy1 : X1;
            unsigned w2 = hi ? Y0 : sx0;
            unsigned w3 = hi ? Y1 : sx1;
            int4 wi = make_int4((int)w0, (int)w1, (int)w2, (int)w3);
            short8 pb = *(short8*)&wi;

            __builtin_amdgcn_s_setprio(1);
            acc_l = __builtin_amdgcn_mfma_f32_32x32x16_bf16(ones, pb, acc_l, 0, 0, 0);
            short8 vf0 = *(const short8*)&Vs[cur][l31][k2 * 16 + hi8];
            short8 vf1 = *(const short8*)&Vs[cur][32 + l31][k2 * 16 + hi8];
            acc_o[0] = __builtin_amdgcn_mfma_f32_32x32x16_bf16(vf0, pb, acc_o[0], 0, 0, 0);
            acc_o[1] = __builtin_amdgcn_mfma_f32_32x32x16_bf16(vf1, pb, acc_o[1], 0, 0, 0);
            __builtin_amdgcn_s_setprio(0);
        }

        if (t + 1 < L_ / 64) {
            const int nxt = cur ^ 1;
            *(int4*)&Ks[nxt][krow][kseg] = rk0;
            *(int4*)&Ks[nxt][krow][kseg + 8] = rk1;
            *(int4*)&Vs[nxt][krow][kseg] = rv0;
            *(int4*)&Vs[nxt][krow][kseg + 8] = rv1;
        }
    }

    const float il = 1.0f / acc_l[0];
    float* op = attn_out + ((size_t)b * L_ + qrow) * D_ + h * E_ + hi * 4;
#pragma unroll
    for (int et = 0; et < 2; et++)
#pragma unroll
        for (int rg = 0; rg < 4; rg++) {
            float4 ov;
            ov.x = acc_o[et][rg * 4 + 0] * il;
            ov.y = acc_o[et][rg * 4 + 1] * il;
            ov.z = acc_o[et][rg * 4 + 2] * il;
            ov.w = acc_o[et][rg * 4 + 3] * il;
            *(float4*)(op + et * 32 + rg * 8) = ov;
        }
}

// ---------------- residual + layernorm (vectorized), optional second input ----------------
__global__ __launch_bounds__(256) void ln_kernel(const float* __restrict__ A,
                                                 const float* __restrict__ Bres,
                                                 const float* __restrict__ gamma,
                                                 const float* __restrict__ beta,
                                                 float* __restrict__ out_f32,
                                                 bf16* __restrict__ out_bf16) {
    __shared__ float reds[4], reds2[4];
    const int row = blockIdx.x, tid = threadIdx.x;
    const int c4 = tid * 4;
    float4 va = *(const float4*)(A + (size_t)row * D_ + c4);
    if (Bres) {
        float4 vb = *(const float4*)(Bres + (size_t)row * D_ + c4);
        va.x += vb.x; va.y += vb.y; va.z += vb.z; va.w += vb.w;
    }
    float s = va.x + va.y + va.z + va.w;
    float s2 = va.x * va.x + va.y * va.y + va.z * va.z + va.w * va.w;
#pragma unroll
    for (int o = 32; o > 0; o >>= 1) {
        s += __shfl_down(s, o, 64);
        s2 += __shfl_down(s2, o, 64);
    }
    if ((tid & 63) == 0) { reds[tid >> 6] = s; reds2[tid >> 6] = s2; }
    __syncthreads();
    s = reds[0] + reds[1] + reds[2] + reds[3];
    s2 = reds2[0] + reds2[1] + reds2[2] + reds2[3];
    float mean = s * (1.0f / D_);
    float var = s2 * (1.0f / D_) - mean * mean;
    float r = rsqrtf(var + 1e-5f);
    float4 vg = *(const float4*)(gamma + c4);
    float4 vbt = *(const float4*)(beta + c4);
    float4 o;
    o.x = (va.x - mean) * r * vg.x + vbt.x;
    o.y = (va.y - mean) * r * vg.y + vbt.y;
    o.z = (va.z - mean) * r * vg.z + vbt.z;
    o.w = (va.w - mean) * r * vg.w + vbt.w;
    if (out_f32) *(float4*)(out_f32 + (size_t)row * D_ + c4) = o;
    if (out_bf16) {
        unsigned p0 = ((unsigned)(unsigned short)f2bf(o.x)) | (((unsigned)(unsigned short)f2bf(o.y)) << 16);
        unsigned p1 = ((unsigned)(unsigned short)f2bf(o.z)) | (((unsigned)(unsigned short)f2bf(o.w)) << 16);
        int2 pk = make_int2((int)p0, (int)p1);
        *(int2*)((short*)out_bf16 + (size_t)row * D_ + c4) = pk;
    }
}

// ---------------- gemm1: bf16 MFMA, 256x256 tile, 8-wave 4-phase (T1+T2+T3+T5) ----------------
template <int EPI, int BN>
__global__ __launch_bounds__(512, 2) void gemm8p(const bf16* __restrict__ A,
                                                 const bf16* __restrict__ Bw,
                                                 const float* __restrict__ bias,
                                                 const float* __restrict__ RES,
                                                 void* __restrict__ Cout,
                                                 int M, int N, int K) {
    constexpr int WN = BN / 4;
    constexpr int JF = WN / 32;
    constexpr int BISS = BN / 64;
    __shared__ short As[2][256 * 64];
    __shared__ short Bs[2][BN * 64];

    const int tid = threadIdx.x;
    const int wid = tid >> 6, lane = tid & 63;
    const int wr = wid >> 2, wc = wid & 3;
    const int lrow = lane & 15, quad = lane >> 4;

    const int nbx = gridDim.x;
    const int id = blockIdx.y * nbx + blockIdx.x;
    const int chunk = (nbx * gridDim.y) >> 3;
    const int swz = (id & 7) * chunk + (id >> 3);
    const int bn = swz % nbx, bm = swz / nbx;

    const int srow = wid * 8 + (lane >> 3);
    const int scol = ((lane & 7) ^ ((lane >> 3) & 7)) * 8;
    const short* Ag = (const short*)A + (size_t)(bm * 256 + srow) * K + scol;
    const short* Bg = (const short*)Bw + (size_t)(bn * BN + srow) * K + scol;

    f32x4 acc[2][2][4][JF];
#pragma unroll
    for (int qr = 0; qr < 2; qr++)
#pragma unroll
        for (int qc = 0; qc < 2; qc++)
#pragma unroll
            for (int i = 0; i < 4; i++)
#pragma unroll
                for (int j = 0; j < JF; j++) acc[qr][qc][i][j] = (f32x4){0.f, 0.f, 0.f, 0.f};

#define STAGE_A(b, k0)                                                              \
    do {                                                                            \
        _Pragma("unroll") for (int s = 0; s < 4; s++)                               \
            gl_lds16(Ag + (size_t)s * 64 * K + (k0), &As[b][(s * 64 + wid * 8) * 64]); \
    } while (0)
#define STAGE_B(b, k0)                                                              \
    do {                                                                            \
        _Pragma("unroll") for (int s = 0; s < BISS; s++)                            \
            gl_lds16(Bg + (size_t)s * 64 * K + (k0), &Bs[b][(s * 64 + wid * 8) * 64]); \
    } while (0)

#define RD_A(b, R, q) (*(const short8*)&As[b][(R) * 64 + (((q) ^ ((R) & 7)) * 8)])
#define RD_B(b, R, q) (*(const short8*)&Bs[b][(R) * 64 + (((q) ^ ((R) & 7)) * 8)])
#define LGKM0()                                          \
    do {                                                 \
        asm volatile("s_waitcnt lgkmcnt(0)" ::: "memory"); \
        __builtin_amdgcn_sched_barrier(0);               \
    } while (0)

    STAGE_A(0, 0);
    STAGE_B(0, 0);

    const int NT = K / 64;
    for (int t = 0; t < NT; t++) {
        const int p = t & 1;
        asm volatile("s_waitcnt vmcnt(0)" ::: "memory");
        __builtin_amdgcn_s_barrier();
        __builtin_amdgcn_sched_barrier(0);
        const int kn = (t + 1) * 64;
        const bool more = t + 1 < NT;

        short8 afr[4][2], bfr[JF][2];

#pragma unroll
        for (int i = 0; i < 4; i++)
#pragma unroll
            for (int kq = 0; kq < 2; kq++)
                afr[i][kq] = RD_A(p, wr * 128 + i * 16 + lrow, kq * 4 + quad);
#pragma unroll
        for (int j = 0; j < JF; j++)
#pragma unroll
            for (int kq = 0; kq < 2; kq++)
                bfr[j][kq] = RD_B(p, wc * WN + j * 16 + lrow, kq * 4 + quad);
        if (more) STAGE_A(p ^ 1, kn);
        LGKM0();
        __builtin_amdgcn_s_setprio(1);
#pragma unroll
        for (int i = 0; i < 4; i++)
#pragma unroll
            for (int j = 0; j < JF; j++)
#pragma unroll
                for (int kq = 0; kq < 2; kq++)
                    acc[0][0][i][j] = __builtin_amdgcn_mfma_f32_16x16x32_bf16(
                        afr[i][kq], bfr[j][kq], acc[0][0][i][j], 0, 0, 0);
        __builtin_amdgcn_s_setprio(0);
        __builtin_amdgcn_s_barrier();

#pragma unroll
        for (int j = 0; j < JF; j++)
#pragma unroll
            for (int kq = 0; kq < 2; kq++)
                bfr[j][kq] = RD_B(p, wc * WN + WN / 2 + j * 16 + lrow, kq * 4 + quad);
        if (more) STAGE_B(p ^ 1, kn);
        LGKM0();
        __builtin_amdgcn_s_setprio(1);
#pragma unroll
        for (int i = 0; i < 4; i++)
#pragma unroll
            for (int j = 0; j < JF; j++)
#pragma unroll
                for (int kq = 0; kq < 2; kq++)
                    acc[0][1][i][j] = __builtin_amdgcn_mfma_f32_16x16x32_bf16(
                        afr[i][kq], bfr[j][kq], acc[0][1][i][j], 0, 0, 0);
        __builtin_amdgcn_s_setprio(0);
        __builtin_amdgcn_s_barrier();

#pragma unroll
        for (int i = 0; i < 4; i++)
#pragma unroll
            for (int kq = 0; kq < 2; kq++)
                afr[i][kq] = RD_A(p, wr * 128 + 64 + i * 16 + lrow, kq * 4 + quad);
        LGKM0();
        __builtin_amdgcn_s_setprio(1);
#pragma unroll
        for (int i = 0; i < 4; i++)
#pragma unroll
            for (int j = 0; j < JF; j++)
#pragma unroll
                for (int kq = 0; kq < 2; kq++)
                    acc[1][1][i][j] = __builtin_amdgcn_mfma_f32_16x16x32_bf16(
                        afr[i][kq], bfr[j][kq], acc[1][1][i][j], 0, 0, 0);
        __builtin_amdgcn_s_setprio(0);
        __builtin_amdgcn_s_barrier();

#pragma unroll
        for (int j = 0; j < JF; j++)
#pragma unroll
            for (int kq = 0; kq < 2; kq++)
                bfr[j][kq] = RD_B(p, wc * WN + j * 16 + lrow, kq * 4 + quad);
        LGKM0();
        __builtin_amdgcn_s_setprio(1);
#pragma unroll
        for (int i = 0; i < 4; i++)
#pragma unroll
            for (int j = 0; j < JF; j++)
#pragma unroll
                for (int kq = 0; kq < 2; kq++)
                    acc[1][0][i][j] = __builtin_amdgcn_mfma_f32_16x16x32_bf16(
                        afr[i][kq], bfr[j][kq], acc[1][0][i][j], 0, 0, 0);
        __builtin_amdgcn_s_setprio(0);
    }
#undef STAGE_A
#undef STAGE_B
#undef RD_A
#undef RD_B
#undef LGKM0

#pragma unroll
    for (int qr = 0; qr < 2; qr++)
#pragma unroll
        for (int qc = 0; qc < 2; qc++)
#pragma unroll
            for (int i = 0; i < 4; i++)
#pragma unroll
                for (int j = 0; j < JF; j++) {
                    int col = bn * BN + wc * WN + qc * (WN / 2) + j * 16 + lrow;
                    float bv = bias[col];
#pragma unroll
                    for (int r = 0; r < 4; r++) {
                        int row = bm * 256 + wr * 128 + qr * 64 + i * 16 + quad * 4 + r;
                        float v = acc[qr][qc][i][j][r] + bv;
                        if (EPI == 0) {
                            v = fmaxf(v, 0.f);
                            ((bf16*)Cout)[(size_t)row * N + col] = __float2bfloat16(v);
                        } else if (EPI == 1) {
                            ((float*)Cout)[(size_t)row * N + col] = v;
                        } else {
                            v += RES[(size_t)row * N + col];
                            ((float*)Cout)[(size_t)row * N + col] = v;
                        }
                    }
                }
}

// ---------------- gemm2: 256x128 tile, 8 waves 4Mx2N, 3-deep buffers, counted vmcnt ----------------
// Per-wave output 64x64 (no A-fragment cross-wave duplication beyond 2x, no quadrant re-reads).
// K-tile t+2 staged while computing t; vmcnt(6) at top (= tile t+1's 6 issues stay in flight).
// ONE barrier per K-tile. Hazards: reads buf[t%3], writes buf[(t+2)%3] (disjoint); WAR across
// iterations sequenced by the top barrier (reads drained by lgkmcnt(0) before each MFMA cluster).
__global__ __launch_bounds__(512, 1) void gemm2_k(const bf16* __restrict__ A,
                                                  const bf16* __restrict__ Bw,
                                                  const float* __restrict__ bias,
                                                  const float* __restrict__ RES,
                                                  float* __restrict__ Cout,
                                                  int M, int N, int K) {
    __shared__ short As[3][256 * 64];
    __shared__ short Bs[3][128 * 64];

    const int tid = threadIdx.x;
    const int wid = tid >> 6, lane = tid & 63;
    const int wr = wid >> 1, wc = wid & 1;       // 4M x 2N waves, 64x64 out each
    const int lrow = lane & 15, quad = lane >> 4;

    // T1 bijective XCD swizzle (grid = 8 x 32 = 256 wg, %8==0)
    const int nbx = gridDim.x;
    const int id = blockIdx.y * nbx + blockIdx.x;
    const int chunk = (nbx * gridDim.y) >> 3;
    const int swz = (id & 7) * chunk + (id >> 3);
    const int bn = swz % nbx, bm = swz / nbx;

    const int srow = wid * 8 + (lane >> 3);
    const int scol = ((lane & 7) ^ ((lane >> 3) & 7)) * 8;   // pre-permuted source (T2, rule 21)
    const short* Ag = (const short*)A + (size_t)(bm * 256 + srow) * K + scol;
    const short* Bg = (const short*)Bw + (size_t)(bn * 128 + srow) * K + scol;

    f32x4 acc[4][4];
#pragma unroll
    for (int i = 0; i < 4; i++)
#pragma unroll
        for (int j = 0; j < 4; j++) acc[i][j] = (f32x4){0.f, 0.f, 0.f, 0.f};

#define STAGE2_A(dst, k0)                                                            \
    do {                                                                             \
        _Pragma("unroll") for (int s = 0; s < 4; s++)                                \
            gl_lds16(Ag + (size_t)s * 64 * K + (k0), (dst) + (s * 64 + wid * 8) * 64); \
    } while (0)
#define STAGE2_B(dst, k0)                                                            \
    do {                                                                             \
        _Pragma("unroll") for (int s = 0; s < 2; s++)                                \
            gl_lds16(Bg + (size_t)s * 64 * K + (k0), (dst) + (s * 64 + wid * 8) * 64); \
    } while (0)
#define RD2(base, R, q) (*(const short8*)&(base)[(R) * 64 + (((q) ^ ((R) & 7)) * 8)])
#define LGKM0()                                            \
    do {                                                   \
        asm volatile("s_waitcnt lgkmcnt(0)" ::: "memory"); \
        __builtin_amdgcn_sched_barrier(0);                 \
    } while (0)

    short* a0 = &As[0][0];
    short* a1 = &As[1][0];
    short* a2 = &As[2][0];
    short* b0 = &Bs[0][0];
    short* b1 = &Bs[1][0];
    short* b2 = &Bs[2][0];

    // prologue: tiles 0 and 1 in flight (A-then-B issue order per tile, 6 each)
    STAGE2_A(a0, 0);
    STAGE2_B(b0, 0);
    STAGE2_A(a1, 64);
    STAGE2_B(b1, 64);

    const int NT = K / 64;
    for (int t = 0; t < NT; t++) {
        if (t < NT - 1)
            asm volatile("s_waitcnt vmcnt(6)" ::: "memory");   // tile t landed; t+1 in flight
        else
            asm volatile("s_waitcnt vmcnt(0)" ::: "memory");
        __builtin_amdgcn_s_barrier();
        __builtin_amdgcn_sched_barrier(0);
        const bool more = t + 2 < NT;
        const int kn = (t + 2) * 64;

        short8 afr[4][2], bfr[4][2];
        // phase 0: all A frags + B j=0,1 ; stage A(t+2)
#pragma unroll
        for (int i = 0; i < 4; i++)
#pragma unroll
            for (int kq = 0; kq < 2; kq++)
                afr[i][kq] = RD2(a0, wr * 64 + i * 16 + lrow, kq * 4 + quad);
#pragma unroll
        for (int j = 0; j < 2; j++)
#pragma unroll
            for (int kq = 0; kq < 2; kq++)
                bfr[j][kq] = RD2(b0, wc * 64 + j * 16 + lrow, kq * 4 + quad);
        if (more) STAGE2_A(a2, kn);
        LGKM0();
        __builtin_amdgcn_s_setprio(1);
#pragma unroll
        for (int i = 0; i < 4; i++)
#pragma unroll
            for (int j = 0; j < 2; j++)
#pragma unroll
                for (int kq = 0; kq < 2; kq++)
                    acc[i][j] = __builtin_amdgcn_mfma_f32_16x16x32_bf16(
                        afr[i][kq], bfr[j][kq], acc[i][j], 0, 0, 0);
        __builtin_amdgcn_s_setprio(0);

        // phase 1: B j=2,3 ; stage B(t+2)
#pragma unroll
        for (int j = 2; j < 4; j++)
#pragma unroll
            for (int kq = 0; kq < 2; kq++)
                bfr[j][kq] = RD2(b0, wc * 64 + j * 16 + lrow, kq * 4 + quad);
        if (more) STAGE2_B(b2, kn);
        LGKM0();
        __builtin_amdgcn_s_setprio(1);
#pragma unroll
        for (int i = 0; i < 4; i++)
#pragma unroll
            for (int j = 2; j < 4; j++)
#pragma unroll
                for (int kq = 0; kq < 2; kq++)
                    acc[i][j] = __builtin_amdgcn_mfma_f32_16x16x32_bf16(
                        afr[i][kq], bfr[j][kq], acc[i][j], 0, 0, 0);
        __builtin_amdgcn_s_setprio(0);

        // rotate buffers: (0,1,2) <- (1,2,0)
        short* ta = a0; a0 = a1; a1 = a2; a2 = ta;
        short* tb = b0; b0 = b1; b1 = b2; b2 = tb;
    }
#undef STAGE2_A
#undef STAGE2_B
#undef RD2
#undef LGKM0

    // epilogue: fp32 out + residual
#pragma unroll
    for (int i = 0; i < 4; i++)
#pragma unroll
        for (int j = 0; j < 4; j++) {
            int col = bn * 128 + wc * 64 + j * 16 + lrow;
            float bv = bias[col];
#pragma unroll
            for (int r = 0; r < 4; r++) {
                int row = bm * 256 + wr * 64 + i * 16 + quad * 4 + r;
                float v = acc[i][j][r] + bv + RES[(size_t)row * N + col];
                Cout[(size_t)row * N + col] = v;
            }
        }
}

// ---------------- launch ----------------
extern "C" void kernel_launch(void* const* d_in, const int* in_sizes, int n_in,
                              void* d_out, int out_size, void* d_ws, size_t ws_size,
                              hipStream_t stream) {
    const float* x = (const float*)d_in[0];
    const float* w1 = (const float*)d_in[1];
    const float* b1 = (const float*)d_in[2];
    const float* w2 = (const float*)d_in[3];
    const float* b2 = (const float*)d_in[4];
    const float* g1 = (const float*)d_in[5];
    const float* be1 = (const float*)d_in[6];
    const float* g2 = (const float*)d_in[7];
    const float* be2 = (const float*)d_in[8];
    float* out = (float*)d_out;

    char* ws = (char*)d_ws;
    const size_t MB = 1024 * 1024;
    float* attn_out = (float*)(ws);            // 32 MiB
    float* x1 = (float*)(ws + 32 * MB);        // 32 MiB
    bf16* x1b = (bf16*)(ws + 64 * MB);         // 16 MiB
    bf16* w1b = (bf16*)(ws + 80 * MB);         // 8 MiB
    bf16* w2b = (bf16*)(ws + 88 * MB);         // 8 MiB
    bf16* hb = (bf16*)(ws + 96 * MB);          // 64 MiB (GEMM phase)
    // attention-phase buffers alias hb's region (dead once gemm1 runs):
    short* xb = (short*)(ws + 96 * MB);        // 16 MiB bf16 x
    short* vt = (short*)(ws + 112 * MB);       // 16 MiB bf16 x^T per (b,h)
    float* y2 = attn_out;                      // reuse

    convert_bf16_kernel<<<4096, 256, 0, stream>>>(w1, w1b, F_ * D_);
    convert_bf16_kernel<<<4096, 256, 0, stream>>>(w2, w2b, D_ * F_);
    transpose_vt_kernel<<<dim3(B_ * H_, L_ / 64), 256, 0, stream>>>(x, vt, xb);

    flash_attn_kernel<<<B_ * H_ * (L_ / 128), 256, 0, stream>>>(x, xb, vt, attn_out);

    ln_kernel<<<B_ * L_, 256, 0, stream>>>(x, attn_out, g1, be1, x1, x1b);

    // gemm1: M=8192, N=4096, K=1024 -> grid 16 x 32 = 512 wg
    gemm8p<0, 256><<<dim3(F_ / 256, (B_ * L_) / 256), 512, 0, stream>>>(
        x1b, w1b, b1, nullptr, (void*)hb, B_ * L_, F_, D_);
    // gemm2: M=8192, N=1024, K=4096 -> grid 8 x 32 = 256 wg (1/CU), 3-deep pipeline
    gemm2_k<<<dim3(D_ / 128, (B_ * L_) / 256), 512, 0, stream>>>(
        hb, w2b, b2, x1, y2, B_ * L_, D_, F_);

    ln_kernel<<<B_ * L_, 256, 0, stream>>>(y2, nullptr, g2, be2, out, nullptr);
}

// Round 6
// 268.160 us; speedup vs baseline: 1.1723x; 1.0251x over previous
//
#include <hip/hip_runtime.h>
#include <hip/hip_bf16.h>

#define B_ 4
#define L_ 2048
#define D_ 1024
#define F_ 4096
#define H_ 16
#define E_ 64

typedef __hip_bfloat16 bf16;
typedef __attribute__((ext_vector_type(8))) short short8;
typedef __attribute__((ext_vector_type(4))) float f32x4;
typedef __attribute__((ext_vector_type(16))) float f32x16;

__device__ __forceinline__ short f2bf(float f) {
    union { float f; unsigned u; } v;
    v.f = f;
    unsigned r = (v.u + 0x7fff + ((v.u >> 16) & 1)) >> 16;
    return (short)r;
}

// async global->LDS, 16B per lane, lands at ldsbase + lane*16
__device__ __forceinline__ void gl_lds16(const short* g, short* l) {
    __builtin_amdgcn_global_load_lds((const __attribute__((address_space(1))) void*)g,
                                     (__attribute__((address_space(3))) void*)l, 16, 0, 0);
}

// ---------------- fp32 -> bf16 convert ----------------
__global__ __launch_bounds__(256) void convert_bf16_kernel(const float* __restrict__ src,
                                                           bf16* __restrict__ dst, int n) {
    int i = (blockIdx.x * 256 + threadIdx.x) * 4;
    if (i + 3 < n) {
        float4 v = *(const float4*)(src + i);
        dst[i + 0] = __float2bfloat16(v.x);
        dst[i + 1] = __float2bfloat16(v.y);
        dst[i + 2] = __float2bfloat16(v.z);
        dst[i + 3] = __float2bfloat16(v.w);
    }
}

// ---------------- V^T pre-pass + bf16 x copy ----------------
__global__ __launch_bounds__(256) void transpose_vt_kernel(const float* __restrict__ x,
                                                           short* __restrict__ vt,
                                                           short* __restrict__ xb) {
    __shared__ float tile[64][65];
    const int bh = blockIdx.x, lt = blockIdx.y;
    const int b = bh >> 4, h = bh & 15;
    const int l0 = lt * 64;
    for (int idx = threadIdx.x; idx < 4096; idx += 256) {
        int r = idx >> 6, c = idx & 63;
        float v = x[((size_t)b * L_ + l0 + r) * D_ + h * E_ + c];
        tile[r][c] = v;
        xb[((size_t)b * L_ + l0 + r) * D_ + h * E_ + c] = f2bf(v);
    }
    __syncthreads();
    for (int idx = threadIdx.x; idx < 4096; idx += 256) {
        int e = idx >> 6, l = idx & 63;
        vt[((size_t)bh * E_ + e) * L_ + l0 + l] = f2bf(tile[l][e]);
    }
}

// ---------------- flash attention, swapped-operand 32x32 MFMA, in-register P ----------------
// grid 1024 blocks; XCD-grouping swizzle: xcd = id&7 owns 8 heads (4MB K/V = its L2).
// l-sum kept as per-lane f32 scalar (lane = q column); hi-pair combined in epilogue.
// P redistribute via v_permlane32_swap_b32 (replaces shfl_xor + cndmask).
__global__ __launch_bounds__(256, 4) void flash_attn_kernel(const float* __restrict__ x,
                                                            const short* __restrict__ xb,
                                                            const short* __restrict__ vt,
                                                            float* __restrict__ attn_out) {
    __shared__ short Ks[2][64][72];   // [buf][s][e]
    __shared__ short Vs[2][64][72];   // [buf][e][s]

    const int tid = threadIdx.x;
    const int w = tid >> 6, lane = tid & 63;
    const int l31 = lane & 31;
    const int hi = lane >> 5;
    const int hi8 = hi * 8;

    // XCD-grouping bijection: blocks of one (b,h) stay on one XCD
    const int orig = blockIdx.x;
    const int xcd = orig & 7;
    const int seq = orig >> 3;
    const int qt = seq & 15;
    const int bh = ((seq >> 4) << 3) | xcd;
    const int b = bh >> 4, h = bh & 15;
    const int q0 = qt * 128;

    const short* kbase = xb + (size_t)b * L_ * D_ + h * E_;

    const float QS = 0.125f * 1.44269504f;
    const int qrow = q0 + w * 32 + l31;
    short8 qf[4];
    {
        const float* qp = x + ((size_t)b * L_ + qrow) * D_ + h * E_;
#pragma unroll
        for (int ks = 0; ks < 4; ks++) {
            float4 v0 = *(const float4*)(qp + ks * 16 + hi8);
            float4 v1 = *(const float4*)(qp + ks * 16 + hi8 + 4);
            short8 sc;
            sc[0] = f2bf(v0.x * QS); sc[1] = f2bf(v0.y * QS);
            sc[2] = f2bf(v0.z * QS); sc[3] = f2bf(v0.w * QS);
            sc[4] = f2bf(v1.x * QS); sc[5] = f2bf(v1.y * QS);
            sc[6] = f2bf(v1.z * QS); sc[7] = f2bf(v1.w * QS);
            qf[ks] = sc;
        }
    }

    f32x16 acc_o[2];
    float lsum = 0.f;
#pragma unroll
    for (int r = 0; r < 16; r++) { acc_o[0][r] = 0.f; acc_o[1][r] = 0.f; }

    const int krow = tid >> 2, kseg = (tid & 3) * 16;

    int4 rk0, rk1, rv0, rv1;
    {
        const short* ks = kbase + (size_t)krow * D_ + kseg;
        rk0 = *(const int4*)ks;
        rk1 = *(const int4*)(ks + 8);
        const short* vs = vt + ((size_t)bh * E_ + krow) * L_ + kseg;
        rv0 = *(const int4*)vs;
        rv1 = *(const int4*)(vs + 8);
    }
    *(int4*)&Ks[0][krow][kseg] = rk0;
    *(int4*)&Ks[0][krow][kseg + 8] = rk1;
    *(int4*)&Vs[0][krow][kseg] = rv0;
    *(int4*)&Vs[0][krow][kseg + 8] = rv1;

    for (int t = 0; t < L_ / 64; t++) {
        const int cur = t & 1;
        __syncthreads();

        if (t + 1 < L_ / 64) {
            const short* ks = kbase + (size_t)((t + 1) * 64 + krow) * D_ + kseg;
            rk0 = *(const int4*)ks;
            rk1 = *(const int4*)(ks + 8);
            const short* vs = vt + ((size_t)bh * E_ + krow) * L_ + (t + 1) * 64 + kseg;
            rv0 = *(const int4*)vs;
            rv1 = *(const int4*)(vs + 8);
        }

        f32x16 accp0, accp1;
#pragma unroll
        for (int r = 0; r < 16; r++) { accp0[r] = 0.f; accp1[r] = 0.f; }
        __builtin_amdgcn_s_setprio(1);
#pragma unroll
        for (int ks = 0; ks < 4; ks++) {
            short8 kf0 = *(const short8*)&Ks[cur][l31][ks * 16 + hi8];
            short8 kf1 = *(const short8*)&Ks[cur][32 + l31][ks * 16 + hi8];
            accp0 = __builtin_amdgcn_mfma_f32_32x32x16_bf16(kf0, qf[ks], accp0, 0, 0, 0);
            accp1 = __builtin_amdgcn_mfma_f32_32x32x16_bf16(kf1, qf[ks], accp1, 0, 0, 0);
        }
        __builtin_amdgcn_s_setprio(0);

        float pe[2][16];
#pragma unroll
        for (int r = 0; r < 16; r++) {
            pe[0][r] = __builtin_amdgcn_exp2f(accp0[r]);
            pe[1][r] = __builtin_amdgcn_exp2f(accp1[r]);
        }
        // per-lane l partial: lane owns q=l31 column; own 32 of 64 s-rows (partner has rest)
#pragma unroll
        for (int r = 0; r < 16; r++) lsum += pe[0][r] + pe[1][r];

#pragma unroll
        for (int k2 = 0; k2 < 4; k2++) {
            const int tt = k2 >> 1, o = (k2 & 1) * 8;
            unsigned X0, X1, Y0, Y1;
            asm("v_cvt_pk_bf16_f32 %0, %1, %2" : "=v"(X0) : "v"(pe[tt][o + 0]), "v"(pe[tt][o + 1]));
            asm("v_cvt_pk_bf16_f32 %0, %1, %2" : "=v"(X1) : "v"(pe[tt][o + 2]), "v"(pe[tt][o + 3]));
            asm("v_cvt_pk_bf16_f32 %0, %1, %2" : "=v"(Y0) : "v"(pe[tt][o + 4]), "v"(pe[tt][o + 5]));
            asm("v_cvt_pk_bf16_f32 %0, %1, %2" : "=v"(Y1) : "v"(pe[tt][o + 6]), "v"(pe[tt][o + 7]));
            // swap vdst.hi <-> vsrc.lo: X' = {X.lo, Y.lo} (= old hi?sy:X), Y' = {X.hi, Y.hi} (= old hi?Y:sx)
            asm("v_permlane32_swap_b32 %0, %1" : "+v"(X0), "+v"(Y0));
            asm("v_permlane32_swap_b32 %0, %1" : "+v"(X1), "+v"(Y1));
            int4 wi = make_int4((int)X0, (int)X1, (int)Y0, (int)Y1);
            short8 pb = *(short8*)&wi;

            __builtin_amdgcn_s_setprio(1);
            short8 vf0 = *(const short8*)&Vs[cur][l31][k2 * 16 + hi8];
            short8 vf1 = *(const short8*)&Vs[cur][32 + l31][k2 * 16 + hi8];
            acc_o[0] = __builtin_amdgcn_mfma_f32_32x32x16_bf16(vf0, pb, acc_o[0], 0, 0, 0);
            acc_o[1] = __builtin_amdgcn_mfma_f32_32x32x16_bf16(vf1, pb, acc_o[1], 0, 0, 0);
            __builtin_amdgcn_s_setprio(0);
        }

        if (t + 1 < L_ / 64) {
            const int nxt = cur ^ 1;
            *(int4*)&Ks[nxt][krow][kseg] = rk0;
            *(int4*)&Ks[nxt][krow][kseg + 8] = rk1;
            *(int4*)&Vs[nxt][krow][kseg] = rv0;
            *(int4*)&Vs[nxt][krow][kseg + 8] = rv1;
        }
    }

    // epilogue: O /= l.  l = own partial + hi-partner partial (same q column).
    const float ltot = lsum + __shfl_xor(lsum, 32, 64);
    const float il = 1.0f / ltot;
    float* op = attn_out + ((size_t)b * L_ + qrow) * D_ + h * E_ + hi * 4;
#pragma unroll
    for (int et = 0; et < 2; et++)
#pragma unroll
        for (int rg = 0; rg < 4; rg++) {
            float4 ov;
            ov.x = acc_o[et][rg * 4 + 0] * il;
            ov.y = acc_o[et][rg * 4 + 1] * il;
            ov.z = acc_o[et][rg * 4 + 2] * il;
            ov.w = acc_o[et][rg * 4 + 3] * il;
            *(float4*)(op + et * 32 + rg * 8) = ov;
        }
}

// ---------------- residual + layernorm (vectorized), optional second input ----------------
__global__ __launch_bounds__(256) void ln_kernel(const float* __restrict__ A,
                                                 const float* __restrict__ Bres,
                                                 const float* __restrict__ gamma,
                                                 const float* __restrict__ beta,
                                                 float* __restrict__ out_f32,
                                                 bf16* __restrict__ out_bf16) {
    __shared__ float reds[4], reds2[4];
    const int row = blockIdx.x, tid = threadIdx.x;
    const int c4 = tid * 4;
    float4 va = *(const float4*)(A + (size_t)row * D_ + c4);
    if (Bres) {
        float4 vb = *(const float4*)(Bres + (size_t)row * D_ + c4);
        va.x += vb.x; va.y += vb.y; va.z += vb.z; va.w += vb.w;
    }
    float s = va.x + va.y + va.z + va.w;
    float s2 = va.x * va.x + va.y * va.y + va.z * va.z + va.w * va.w;
#pragma unroll
    for (int o = 32; o > 0; o >>= 1) {
        s += __shfl_down(s, o, 64);
        s2 += __shfl_down(s2, o, 64);
    }
    if ((tid & 63) == 0) { reds[tid >> 6] = s; reds2[tid >> 6] = s2; }
    __syncthreads();
    s = reds[0] + reds[1] + reds[2] + reds[3];
    s2 = reds2[0] + reds2[1] + reds2[2] + reds2[3];
    float mean = s * (1.0f / D_);
    float var = s2 * (1.0f / D_) - mean * mean;
    float r = rsqrtf(var + 1e-5f);
    float4 vg = *(const float4*)(gamma + c4);
    float4 vbt = *(const float4*)(beta + c4);
    float4 o;
    o.x = (va.x - mean) * r * vg.x + vbt.x;
    o.y = (va.y - mean) * r * vg.y + vbt.y;
    o.z = (va.z - mean) * r * vg.z + vbt.z;
    o.w = (va.w - mean) * r * vg.w + vbt.w;
    if (out_f32) *(float4*)(out_f32 + (size_t)row * D_ + c4) = o;
    if (out_bf16) {
        unsigned p0 = ((unsigned)(unsigned short)f2bf(o.x)) | (((unsigned)(unsigned short)f2bf(o.y)) << 16);
        unsigned p1 = ((unsigned)(unsigned short)f2bf(o.z)) | (((unsigned)(unsigned short)f2bf(o.w)) << 16);
        int2 pk = make_int2((int)p0, (int)p1);
        *(int2*)((short*)out_bf16 + (size_t)row * D_ + c4) = pk;
    }
}

// ---------------- gemm1: bf16 MFMA, 256x256 tile, 8-wave 4-phase (T1+T2+T3+T5) ----------------
template <int EPI, int BN>
__global__ __launch_bounds__(512, 2) void gemm8p(const bf16* __restrict__ A,
                                                 const bf16* __restrict__ Bw,
                                                 const float* __restrict__ bias,
                                                 const float* __restrict__ RES,
                                                 void* __restrict__ Cout,
                                                 int M, int N, int K) {
    constexpr int WN = BN / 4;
    constexpr int JF = WN / 32;
    constexpr int BISS = BN / 64;
    __shared__ short As[2][256 * 64];
    __shared__ short Bs[2][BN * 64];

    const int tid = threadIdx.x;
    const int wid = tid >> 6, lane = tid & 63;
    const int wr = wid >> 2, wc = wid & 3;
    const int lrow = lane & 15, quad = lane >> 4;

    const int nbx = gridDim.x;
    const int id = blockIdx.y * nbx + blockIdx.x;
    const int chunk = (nbx * gridDim.y) >> 3;
    const int swz = (id & 7) * chunk + (id >> 3);
    const int bn = swz % nbx, bm = swz / nbx;

    const int srow = wid * 8 + (lane >> 3);
    const int scol = ((lane & 7) ^ ((lane >> 3) & 7)) * 8;
    const short* Ag = (const short*)A + (size_t)(bm * 256 + srow) * K + scol;
    const short* Bg = (const short*)Bw + (size_t)(bn * BN + srow) * K + scol;

    f32x4 acc[2][2][4][JF];
#pragma unroll
    for (int qr = 0; qr < 2; qr++)
#pragma unroll
        for (int qc = 0; qc < 2; qc++)
#pragma unroll
            for (int i = 0; i < 4; i++)
#pragma unroll
                for (int j = 0; j < JF; j++) acc[qr][qc][i][j] = (f32x4){0.f, 0.f, 0.f, 0.f};

#define STAGE_A(b, k0)                                                              \
    do {                                                                            \
        _Pragma("unroll") for (int s = 0; s < 4; s++)                               \
            gl_lds16(Ag + (size_t)s * 64 * K + (k0), &As[b][(s * 64 + wid * 8) * 64]); \
    } while (0)
#define STAGE_B(b, k0)                                                              \
    do {                                                                            \
        _Pragma("unroll") for (int s = 0; s < BISS; s++)                            \
            gl_lds16(Bg + (size_t)s * 64 * K + (k0), &Bs[b][(s * 64 + wid * 8) * 64]); \
    } while (0)

#define RD_A(b, R, q) (*(const short8*)&As[b][(R) * 64 + (((q) ^ ((R) & 7)) * 8)])
#define RD_B(b, R, q) (*(const short8*)&Bs[b][(R) * 64 + (((q) ^ ((R) & 7)) * 8)])
#define LGKM0()                                          \
    do {                                                 \
        asm volatile("s_waitcnt lgkmcnt(0)" ::: "memory"); \
        __builtin_amdgcn_sched_barrier(0);               \
    } while (0)

    STAGE_A(0, 0);
    STAGE_B(0, 0);

    const int NT = K / 64;
    for (int t = 0; t < NT; t++) {
        const int p = t & 1;
        asm volatile("s_waitcnt vmcnt(0)" ::: "memory");
        __builtin_amdgcn_s_barrier();
        __builtin_amdgcn_sched_barrier(0);
        const int kn = (t + 1) * 64;
        const bool more = t + 1 < NT;

        short8 afr[4][2], bfr[JF][2];

#pragma unroll
        for (int i = 0; i < 4; i++)
#pragma unroll
            for (int kq = 0; kq < 2; kq++)
                afr[i][kq] = RD_A(p, wr * 128 + i * 16 + lrow, kq * 4 + quad);
#pragma unroll
        for (int j = 0; j < JF; j++)
#pragma unroll
            for (int kq = 0; kq < 2; kq++)
                bfr[j][kq] = RD_B(p, wc * WN + j * 16 + lrow, kq * 4 + quad);
        if (more) STAGE_A(p ^ 1, kn);
        LGKM0();
        __builtin_amdgcn_s_setprio(1);
#pragma unroll
        for (int i = 0; i < 4; i++)
#pragma unroll
            for (int j = 0; j < JF; j++)
#pragma unroll
                for (int kq = 0; kq < 2; kq++)
                    acc[0][0][i][j] = __builtin_amdgcn_mfma_f32_16x16x32_bf16(
                        afr[i][kq], bfr[j][kq], acc[0][0][i][j], 0, 0, 0);
        __builtin_amdgcn_s_setprio(0);
        __builtin_amdgcn_s_barrier();

#pragma unroll
        for (int j = 0; j < JF; j++)
#pragma unroll
            for (int kq = 0; kq < 2; kq++)
                bfr[j][kq] = RD_B(p, wc * WN + WN / 2 + j * 16 + lrow, kq * 4 + quad);
        if (more) STAGE_B(p ^ 1, kn);
        LGKM0();
        __builtin_amdgcn_s_setprio(1);
#pragma unroll
        for (int i = 0; i < 4; i++)
#pragma unroll
            for (int j = 0; j < JF; j++)
#pragma unroll
                for (int kq = 0; kq < 2; kq++)
                    acc[0][1][i][j] = __builtin_amdgcn_mfma_f32_16x16x32_bf16(
                        afr[i][kq], bfr[j][kq], acc[0][1][i][j], 0, 0, 0);
        __builtin_amdgcn_s_setprio(0);
        __builtin_amdgcn_s_barrier();

#pragma unroll
        for (int i = 0; i < 4; i++)
#pragma unroll
            for (int kq = 0; kq < 2; kq++)
                afr[i][kq] = RD_A(p, wr * 128 + 64 + i * 16 + lrow, kq * 4 + quad);
        LGKM0();
        __builtin_amdgcn_s_setprio(1);
#pragma unroll
        for (int i = 0; i < 4; i++)
#pragma unroll
            for (int j = 0; j < JF; j++)
#pragma unroll
                for (int kq = 0; kq < 2; kq++)
                    acc[1][1][i][j] = __builtin_amdgcn_mfma_f32_16x16x32_bf16(
                        afr[i][kq], bfr[j][kq], acc[1][1][i][j], 0, 0, 0);
        __builtin_amdgcn_s_setprio(0);
        __builtin_amdgcn_s_barrier();

#pragma unroll
        for (int j = 0; j < JF; j++)
#pragma unroll
            for (int kq = 0; kq < 2; kq++)
                bfr[j][kq] = RD_B(p, wc * WN + j * 16 + lrow, kq * 4 + quad);
        LGKM0();
        __builtin_amdgcn_s_setprio(1);
#pragma unroll
        for (int i = 0; i < 4; i++)
#pragma unroll
            for (int j = 0; j < JF; j++)
#pragma unroll
                for (int kq = 0; kq < 2; kq++)
                    acc[1][0][i][j] = __builtin_amdgcn_mfma_f32_16x16x32_bf16(
                        afr[i][kq], bfr[j][kq], acc[1][0][i][j], 0, 0, 0);
        __builtin_amdgcn_s_setprio(0);
    }
#undef STAGE_A
#undef STAGE_B
#undef RD_A
#undef RD_B
#undef LGKM0

#pragma unroll
    for (int qr = 0; qr < 2; qr++)
#pragma unroll
        for (int qc = 0; qc < 2; qc++)
#pragma unroll
            for (int i = 0; i < 4; i++)
#pragma unroll
                for (int j = 0; j < JF; j++) {
                    int col = bn * BN + wc * WN + qc * (WN / 2) + j * 16 + lrow;
                    float bv = bias[col];
#pragma unroll
                    for (int r = 0; r < 4; r++) {
                        int row = bm * 256 + wr * 128 + qr * 64 + i * 16 + quad * 4 + r;
                        float v = acc[qr][qc][i][j][r] + bv;
                        if (EPI == 0) {
                            v = fmaxf(v, 0.f);
                            ((bf16*)Cout)[(size_t)row * N + col] = __float2bfloat16(v);
                        } else if (EPI == 1) {
                            ((float*)Cout)[(size_t)row * N + col] = v;
                        } else {
                            v += RES[(size_t)row * N + col];
                            ((float*)Cout)[(size_t)row * N + col] = v;
                        }
                    }
                }
}

// ---------------- gemm2: 256x128 tile, 8 waves 4Mx2N, 3-deep buffers, counted vmcnt ----------------
__global__ __launch_bounds__(512, 1) void gemm2_k(const bf16* __restrict__ A,
                                                  const bf16* __restrict__ Bw,
                                                  const float* __restrict__ bias,
                                                  const float* __restrict__ RES,
                                                  float* __restrict__ Cout,
                                                  int M, int N, int K) {
    __shared__ short As[3][256 * 64];
    __shared__ short Bs[3][128 * 64];

    const int tid = threadIdx.x;
    const int wid = tid >> 6, lane = tid & 63;
    const int wr = wid >> 1, wc = wid & 1;       // 4M x 2N waves, 64x64 out each
    const int lrow = lane & 15, quad = lane >> 4;

    const int nbx = gridDim.x;
    const int id = blockIdx.y * nbx + blockIdx.x;
    const int chunk = (nbx * gridDim.y) >> 3;
    const int swz = (id & 7) * chunk + (id >> 3);
    const int bn = swz % nbx, bm = swz / nbx;

    const int srow = wid * 8 + (lane >> 3);
    const int scol = ((lane & 7) ^ ((lane >> 3) & 7)) * 8;   // pre-permuted source (T2, rule 21)
    const short* Ag = (const short*)A + (size_t)(bm * 256 + srow) * K + scol;
    const short* Bg = (const short*)Bw + (size_t)(bn * 128 + srow) * K + scol;

    f32x4 acc[4][4];
#pragma unroll
    for (int i = 0; i < 4; i++)
#pragma unroll
        for (int j = 0; j < 4; j++) acc[i][j] = (f32x4){0.f, 0.f, 0.f, 0.f};

#define STAGE2_A(dst, k0)                                                            \
    do {                                                                             \
        _Pragma("unroll") for (int s = 0; s < 4; s++)                                \
            gl_lds16(Ag + (size_t)s * 64 * K + (k0), (dst) + (s * 64 + wid * 8) * 64); \
    } while (0)
#define STAGE2_B(dst, k0)                                                            \
    do {                                                                             \
        _Pragma("unroll") for (int s = 0; s < 2; s++)                                \
            gl_lds16(Bg + (size_t)s * 64 * K + (k0), (dst) + (s * 64 + wid * 8) * 64); \
    } while (0)
#define RD2(base, R, q) (*(const short8*)&(base)[(R) * 64 + (((q) ^ ((R) & 7)) * 8)])
#define LGKM0()                                            \
    do {                                                   \
        asm volatile("s_waitcnt lgkmcnt(0)" ::: "memory"); \
        __builtin_amdgcn_sched_barrier(0);                 \
    } while (0)

    short* a0 = &As[0][0];
    short* a1 = &As[1][0];
    short* a2 = &As[2][0];
    short* b0 = &Bs[0][0];
    short* b1 = &Bs[1][0];
    short* b2 = &Bs[2][0];

    STAGE2_A(a0, 0);
    STAGE2_B(b0, 0);
    STAGE2_A(a1, 64);
    STAGE2_B(b1, 64);

    const int NT = K / 64;
    for (int t = 0; t < NT; t++) {
        if (t < NT - 1)
            asm volatile("s_waitcnt vmcnt(6)" ::: "memory");
        else
            asm volatile("s_waitcnt vmcnt(0)" ::: "memory");
        __builtin_amdgcn_s_barrier();
        __builtin_amdgcn_sched_barrier(0);
        const bool more = t + 2 < NT;
        const int kn = (t + 2) * 64;

        short8 afr[4][2], bfr[4][2];
#pragma unroll
        for (int i = 0; i < 4; i++)
#pragma unroll
            for (int kq = 0; kq < 2; kq++)
                afr[i][kq] = RD2(a0, wr * 64 + i * 16 + lrow, kq * 4 + quad);
#pragma unroll
        for (int j = 0; j < 2; j++)
#pragma unroll
            for (int kq = 0; kq < 2; kq++)
                bfr[j][kq] = RD2(b0, wc * 64 + j * 16 + lrow, kq * 4 + quad);
        if (more) STAGE2_A(a2, kn);
        LGKM0();
        __builtin_amdgcn_s_setprio(1);
#pragma unroll
        for (int i = 0; i < 4; i++)
#pragma unroll
            for (int j = 0; j < 2; j++)
#pragma unroll
                for (int kq = 0; kq < 2; kq++)
                    acc[i][j] = __builtin_amdgcn_mfma_f32_16x16x32_bf16(
                        afr[i][kq], bfr[j][kq], acc[i][j], 0, 0, 0);
        __builtin_amdgcn_s_setprio(0);

#pragma unroll
        for (int j = 2; j < 4; j++)
#pragma unroll
            for (int kq = 0; kq < 2; kq++)
                bfr[j][kq] = RD2(b0, wc * 64 + j * 16 + lrow, kq * 4 + quad);
        if (more) STAGE2_B(b2, kn);
        LGKM0();
        __builtin_amdgcn_s_setprio(1);
#pragma unroll
        for (int i = 0; i < 4; i++)
#pragma unroll
            for (int j = 2; j < 4; j++)
#pragma unroll
                for (int kq = 0; kq < 2; kq++)
                    acc[i][j] = __builtin_amdgcn_mfma_f32_16x16x32_bf16(
                        afr[i][kq], bfr[j][kq], acc[i][j], 0, 0, 0);
        __builtin_amdgcn_s_setprio(0);

        short* ta = a0; a0 = a1; a1 = a2; a2 = ta;
        short* tb = b0; b0 = b1; b1 = b2; b2 = tb;
    }
#undef STAGE2_A
#undef STAGE2_B
#undef RD2
#undef LGKM0

#pragma unroll
    for (int i = 0; i < 4; i++)
#pragma unroll
        for (int j = 0; j < 4; j++) {
            int col = bn * 128 + wc * 64 + j * 16 + lrow;
            float bv = bias[col];
#pragma unroll
            for (int r = 0; r < 4; r++) {
                int row = bm * 256 + wr * 64 + i * 16 + quad * 4 + r;
                float v = acc[i][j][r] + bv + RES[(size_t)row * N + col];
                Cout[(size_t)row * N + col] = v;
            }
        }
}

// ---------------- launch ----------------
extern "C" void kernel_launch(void* const* d_in, const int* in_sizes, int n_in,
                              void* d_out, int out_size, void* d_ws, size_t ws_size,
                              hipStream_t stream) {
    const float* x = (const float*)d_in[0];
    const float* w1 = (const float*)d_in[1];
    const float* b1 = (const float*)d_in[2];
    const float* w2 = (const float*)d_in[3];
    const float* b2 = (const float*)d_in[4];
    const float* g1 = (const float*)d_in[5];
    const float* be1 = (const float*)d_in[6];
    const float* g2 = (const float*)d_in[7];
    const float* be2 = (const float*)d_in[8];
    float* out = (float*)d_out;

    char* ws = (char*)d_ws;
    const size_t MB = 1024 * 1024;
    float* attn_out = (float*)(ws);            // 32 MiB
    float* x1 = (float*)(ws + 32 * MB);        // 32 MiB
    bf16* x1b = (bf16*)(ws + 64 * MB);         // 16 MiB
    bf16* w1b = (bf16*)(ws + 80 * MB);         // 8 MiB
    bf16* w2b = (bf16*)(ws + 88 * MB);         // 8 MiB
    bf16* hb = (bf16*)(ws + 96 * MB);          // 64 MiB (GEMM phase)
    // attention-phase buffers alias hb's region (dead once gemm1 runs):
    short* xb = (short*)(ws + 96 * MB);        // 16 MiB bf16 x
    short* vt = (short*)(ws + 112 * MB);       // 16 MiB bf16 x^T per (b,h)
    float* y2 = attn_out;                      // reuse

    convert_bf16_kernel<<<4096, 256, 0, stream>>>(w1, w1b, F_ * D_);
    convert_bf16_kernel<<<4096, 256, 0, stream>>>(w2, w2b, D_ * F_);
    transpose_vt_kernel<<<dim3(B_ * H_, L_ / 64), 256, 0, stream>>>(x, vt, xb);

    flash_attn_kernel<<<B_ * H_ * (L_ / 128), 256, 0, stream>>>(x, xb, vt, attn_out);

    ln_kernel<<<B_ * L_, 256, 0, stream>>>(x, attn_out, g1, be1, x1, x1b);

    // gemm1: M=8192, N=4096, K=1024 -> grid 16 x 32 = 512 wg
    gemm8p<0, 256><<<dim3(F_ / 256, (B_ * L_) / 256), 512, 0, stream>>>(
        x1b, w1b, b1, nullptr, (void*)hb, B_ * L_, F_, D_);
    // gemm2: M=8192, N=1024, K=4096 -> grid 8 x 32 = 256 wg (1/CU), 3-deep pipeline
    gemm2_k<<<dim3(D_ / 128, (B_ * L_) / 256), 512, 0, stream>>>(
        hb, w2b, b2, x1, y2, B_ * L_, D_, F_);

    ln_kernel<<<B_ * L_, 256, 0, stream>>>(y2, nullptr, g2, be2, out, nullptr);
}

// Round 7
// 260.722 us; speedup vs baseline: 1.2058x; 1.0285x over previous
//
#include <hip/hip_runtime.h>
#include <hip/hip_bf16.h>

#define B_ 4
#define L_ 2048
#define D_ 1024
#define F_ 4096
#define H_ 16
#define E_ 64

typedef __hip_bfloat16 bf16;
typedef __attribute__((ext_vector_type(8))) short short8;
typedef __attribute__((ext_vector_type(4))) float f32x4;
typedef __attribute__((ext_vector_type(16))) float f32x16;

__device__ __forceinline__ short f2bf(float f) {
    union { float f; unsigned u; } v;
    v.f = f;
    unsigned r = (v.u + 0x7fff + ((v.u >> 16) & 1)) >> 16;
    return (short)r;
}

// async global->LDS, 16B per lane, lands at ldsbase + lane*16
__device__ __forceinline__ void gl_lds16(const short* g, short* l) {
    __builtin_amdgcn_global_load_lds((const __attribute__((address_space(1))) void*)g,
                                     (__attribute__((address_space(3))) void*)l, 16, 0, 0);
}

// ---------------- fp32 -> bf16 convert ----------------
__global__ __launch_bounds__(256) void convert_bf16_kernel(const float* __restrict__ src,
                                                           bf16* __restrict__ dst, int n) {
    int i = (blockIdx.x * 256 + threadIdx.x) * 4;
    if (i + 3 < n) {
        float4 v = *(const float4*)(src + i);
        dst[i + 0] = __float2bfloat16(v.x);
        dst[i + 1] = __float2bfloat16(v.y);
        dst[i + 2] = __float2bfloat16(v.z);
        dst[i + 3] = __float2bfloat16(v.w);
    }
}

// ---------------- V^T pre-pass + bf16 x copy ----------------
__global__ __launch_bounds__(256) void transpose_vt_kernel(const float* __restrict__ x,
                                                           short* __restrict__ vt,
                                                           short* __restrict__ xb) {
    __shared__ float tile[64][65];
    const int bh = blockIdx.x, lt = blockIdx.y;
    const int b = bh >> 4, h = bh & 15;
    const int l0 = lt * 64;
    for (int idx = threadIdx.x; idx < 4096; idx += 256) {
        int r = idx >> 6, c = idx & 63;
        float v = x[((size_t)b * L_ + l0 + r) * D_ + h * E_ + c];
        tile[r][c] = v;
        xb[((size_t)b * L_ + l0 + r) * D_ + h * E_ + c] = f2bf(v);
    }
    __syncthreads();
    for (int idx = threadIdx.x; idx < 4096; idx += 256) {
        int e = idx >> 6, l = idx & 63;
        vt[((size_t)bh * E_ + e) * L_ + l0 + l] = f2bf(tile[l][e]);
    }
}

// ---------------- flash attention, swapped-operand 32x32 MFMA, in-register P ----------------
// grid 1024; XCD-grouping swizzle (id&7 owns 8 heads = 4MB K/V = its L2).
// K/V staged via global_load_lds into unpadded KV[2][2][64][64] with T2 XOR swizzle:
//   stage source pre-permuted (chunk_src = (l&7)^((l>>3)&7)), so phys chunk p of row r
//   holds logical chunk p^(r&7); reads XOR a pre-folded per-lane base (1 v_xor per frag).
// Double-buffered; ONE __syncthreads per tile (its vmcnt(0) drains the prefetch issued
// right after the previous barrier -> full compute phase of latency cover).
__global__ __launch_bounds__(256, 4) void flash_attn_kernel(const float* __restrict__ x,
                                                            const short* __restrict__ xb,
                                                            const short* __restrict__ vt,
                                                            float* __restrict__ attn_out) {
    __shared__ short KV[2][2][64][64];   // [buf][K=0/V=1][row][chunk*8]

    const int tid = threadIdx.x;
    const int w = tid >> 6, lane = tid & 63;
    const int l31 = lane & 31;
    const int hi = lane >> 5;
    const int hi8 = hi * 8;

    // XCD-grouping bijection: blocks of one (b,h) stay on one XCD
    const int orig = blockIdx.x;
    const int xcd = orig & 7;
    const int seq = orig >> 3;
    const int qt = seq & 15;
    const int bh = ((seq >> 4) << 3) | xcd;
    const int b = bh >> 4, h = bh & 15;
    const int q0 = qt * 128;

    const short* kbase = xb + (size_t)b * L_ * D_ + h * E_;

    const float QS = 0.125f * 1.44269504f;
    const int qrow = q0 + w * 32 + l31;
    short8 qf[4];
    {
        const float* qp = x + ((size_t)b * L_ + qrow) * D_ + h * E_;
#pragma unroll
        for (int ks = 0; ks < 4; ks++) {
            float4 v0 = *(const float4*)(qp + ks * 16 + hi8);
            float4 v1 = *(const float4*)(qp + ks * 16 + hi8 + 4);
            short8 sc;
            sc[0] = f2bf(v0.x * QS); sc[1] = f2bf(v0.y * QS);
            sc[2] = f2bf(v0.z * QS); sc[3] = f2bf(v0.w * QS);
            sc[4] = f2bf(v1.x * QS); sc[5] = f2bf(v1.y * QS);
            sc[6] = f2bf(v1.z * QS); sc[7] = f2bf(v1.w * QS);
            qf[ks] = sc;
        }
    }

    f32x16 acc_o[2];
    float lsum = 0.f;
#pragma unroll
    for (int r = 0; r < 16; r++) { acc_o[0][r] = 0.f; acc_o[1][r] = 0.f; }

    // staging geometry: wave w covers rows [w*16, w*16+16) of K and of V; 4 issues/wave.
    // source chunk pre-permuted so linear LDS dest holds the swizzled layout (rule 21).
    const int srow = (lane >> 3);                       // 0..7 within 8-row issue group
    const int schunk = ((lane & 7) ^ srow) * 8;         // logical chunk this lane must fetch
    const short* ksrc0 = kbase + (size_t)(w * 16 + srow) * D_ + schunk;
    const short* vsrc0 = vt + ((size_t)bh * E_ + w * 16 + srow) * L_ + schunk;

#define STAGEF(bf_, t_)                                                     \
    do {                                                                    \
        const short* ks_ = ksrc0 + (size_t)(t_) * 64 * D_;                  \
        gl_lds16(ks_, &KV[bf_][0][w * 16][0]);                              \
        gl_lds16(ks_ + (size_t)8 * D_, &KV[bf_][0][w * 16 + 8][0]);         \
        const short* vs_ = vsrc0 + (size_t)(t_) * 64;                       \
        gl_lds16(vs_, &KV[bf_][1][w * 16][0]);                              \
        gl_lds16(vs_ + (size_t)8 * L_, &KV[bf_][1][w * 16 + 8][0]);         \
    } while (0)

    // pre-folded per-lane read base: byte offset of logical chunk 0 (with hi folded)
    // addr(logical frag j) = kvbuf + (p0 ^ (j<<5)) [+4096 row-half | +8192 V | +12288]
    const int p0 = l31 * 128 + ((((l31 & 7) ^ hi)) << 4);

    STAGEF(0, 0);   // prefetch tile 0

    const int NT = L_ / 64;
    for (int t = 0; t < NT; t++) {
        const int cur = t & 1;
        __syncthreads();   // drains vmcnt(0): tile t landed; all prior reads done

        if (t + 1 < NT) STAGEF(cur ^ 1, t + 1);   // covered by the compute below

        const char* kvb = (const char*)&KV[cur][0][0][0];

        f32x16 accp0, accp1;
#pragma unroll
        for (int r = 0; r < 16; r++) { accp0[r] = 0.f; accp1[r] = 0.f; }
        __builtin_amdgcn_s_setprio(1);
#pragma unroll
        for (int j = 0; j < 4; j++) {
            short8 kf0 = *(const short8*)(kvb + (p0 ^ (j << 5)));
            short8 kf1 = *(const short8*)(kvb + 4096 + (p0 ^ (j << 5)));
            accp0 = __builtin_amdgcn_mfma_f32_32x32x16_bf16(kf0, qf[j], accp0, 0, 0, 0);
            accp1 = __builtin_amdgcn_mfma_f32_32x32x16_bf16(kf1, qf[j], accp1, 0, 0, 0);
        }
        __builtin_amdgcn_s_setprio(0);

        float pe[2][16];
#pragma unroll
        for (int r = 0; r < 16; r++) {
            pe[0][r] = __builtin_amdgcn_exp2f(accp0[r]);
            pe[1][r] = __builtin_amdgcn_exp2f(accp1[r]);
        }
#pragma unroll
        for (int r = 0; r < 16; r++) lsum += pe[0][r] + pe[1][r];

#pragma unroll
        for (int j = 0; j < 4; j++) {
            const int tt = j >> 1, o = (j & 1) * 8;
            unsigned X0, X1, Y0, Y1;
            asm("v_cvt_pk_bf16_f32 %0, %1, %2" : "=v"(X0) : "v"(pe[tt][o + 0]), "v"(pe[tt][o + 1]));
            asm("v_cvt_pk_bf16_f32 %0, %1, %2" : "=v"(X1) : "v"(pe[tt][o + 2]), "v"(pe[tt][o + 3]));
            asm("v_cvt_pk_bf16_f32 %0, %1, %2" : "=v"(Y0) : "v"(pe[tt][o + 4]), "v"(pe[tt][o + 5]));
            asm("v_cvt_pk_bf16_f32 %0, %1, %2" : "=v"(Y1) : "v"(pe[tt][o + 6]), "v"(pe[tt][o + 7]));
            asm("v_permlane32_swap_b32 %0, %1" : "+v"(X0), "+v"(Y0));
            asm("v_permlane32_swap_b32 %0, %1" : "+v"(X1), "+v"(Y1));
            int4 wi = make_int4((int)X0, (int)X1, (int)Y0, (int)Y1);
            short8 pb = *(short8*)&wi;

            __builtin_amdgcn_s_setprio(1);
            short8 vf0 = *(const short8*)(kvb + 8192 + (p0 ^ (j << 5)));
            short8 vf1 = *(const short8*)(kvb + 12288 + (p0 ^ (j << 5)));
            acc_o[0] = __builtin_amdgcn_mfma_f32_32x32x16_bf16(vf0, pb, acc_o[0], 0, 0, 0);
            acc_o[1] = __builtin_amdgcn_mfma_f32_32x32x16_bf16(vf1, pb, acc_o[1], 0, 0, 0);
            __builtin_amdgcn_s_setprio(0);
        }
    }
#undef STAGEF

    // epilogue: O /= l.  l = own partial + hi-partner partial (same q column).
    const float ltot = lsum + __shfl_xor(lsum, 32, 64);
    const float il = 1.0f / ltot;
    float* op = attn_out + ((size_t)b * L_ + qrow) * D_ + h * E_ + hi * 4;
#pragma unroll
    for (int et = 0; et < 2; et++)
#pragma unroll
        for (int rg = 0; rg < 4; rg++) {
            float4 ov;
            ov.x = acc_o[et][rg * 4 + 0] * il;
            ov.y = acc_o[et][rg * 4 + 1] * il;
            ov.z = acc_o[et][rg * 4 + 2] * il;
            ov.w = acc_o[et][rg * 4 + 3] * il;
            *(float4*)(op + et * 32 + rg * 8) = ov;
        }
}

// ---------------- residual + layernorm (vectorized), optional second input ----------------
__global__ __launch_bounds__(256) void ln_kernel(const float* __restrict__ A,
                                                 const float* __restrict__ Bres,
                                                 const float* __restrict__ gamma,
                                                 const float* __restrict__ beta,
                                                 float* __restrict__ out_f32,
                                                 bf16* __restrict__ out_bf16) {
    __shared__ float reds[4], reds2[4];
    const int row = blockIdx.x, tid = threadIdx.x;
    const int c4 = tid * 4;
    float4 va = *(const float4*)(A + (size_t)row * D_ + c4);
    if (Bres) {
        float4 vb = *(const float4*)(Bres + (size_t)row * D_ + c4);
        va.x += vb.x; va.y += vb.y; va.z += vb.z; va.w += vb.w;
    }
    float s = va.x + va.y + va.z + va.w;
    float s2 = va.x * va.x + va.y * va.y + va.z * va.z + va.w * va.w;
#pragma unroll
    for (int o = 32; o > 0; o >>= 1) {
        s += __shfl_down(s, o, 64);
        s2 += __shfl_down(s2, o, 64);
    }
    if ((tid & 63) == 0) { reds[tid >> 6] = s; reds2[tid >> 6] = s2; }
    __syncthreads();
    s = reds[0] + reds[1] + reds[2] + reds[3];
    s2 = reds2[0] + reds2[1] + reds2[2] + reds2[3];
    float mean = s * (1.0f / D_);
    float var = s2 * (1.0f / D_) - mean * mean;
    float r = rsqrtf(var + 1e-5f);
    float4 vg = *(const float4*)(gamma + c4);
    float4 vbt = *(const float4*)(beta + c4);
    float4 o;
    o.x = (va.x - mean) * r * vg.x + vbt.x;
    o.y = (va.y - mean) * r * vg.y + vbt.y;
    o.z = (va.z - mean) * r * vg.z + vbt.z;
    o.w = (va.w - mean) * r * vg.w + vbt.w;
    if (out_f32) *(float4*)(out_f32 + (size_t)row * D_ + c4) = o;
    if (out_bf16) {
        unsigned p0 = ((unsigned)(unsigned short)f2bf(o.x)) | (((unsigned)(unsigned short)f2bf(o.y)) << 16);
        unsigned p1 = ((unsigned)(unsigned short)f2bf(o.z)) | (((unsigned)(unsigned short)f2bf(o.w)) << 16);
        int2 pk = make_int2((int)p0, (int)p1);
        *(int2*)((short*)out_bf16 + (size_t)row * D_ + c4) = pk;
    }
}

// ---------------- gemm1: bf16 MFMA, 256x256 tile, 8-wave 4-phase (T1+T2+T3+T5) ----------------
template <int EPI, int BN>
__global__ __launch_bounds__(512, 2) void gemm8p(const bf16* __restrict__ A,
                                                 const bf16* __restrict__ Bw,
                                                 const float* __restrict__ bias,
                                                 const float* __restrict__ RES,
                                                 void* __restrict__ Cout,
                                                 int M, int N, int K) {
    constexpr int WN = BN / 4;
    constexpr int JF = WN / 32;
    constexpr int BISS = BN / 64;
    __shared__ short As[2][256 * 64];
    __shared__ short Bs[2][BN * 64];

    const int tid = threadIdx.x;
    const int wid = tid >> 6, lane = tid & 63;
    const int wr = wid >> 2, wc = wid & 3;
    const int lrow = lane & 15, quad = lane >> 4;

    const int nbx = gridDim.x;
    const int id = blockIdx.y * nbx + blockIdx.x;
    const int chunk = (nbx * gridDim.y) >> 3;
    const int swz = (id & 7) * chunk + (id >> 3);
    const int bn = swz % nbx, bm = swz / nbx;

    const int srow = wid * 8 + (lane >> 3);
    const int scol = ((lane & 7) ^ ((lane >> 3) & 7)) * 8;
    const short* Ag = (const short*)A + (size_t)(bm * 256 + srow) * K + scol;
    const short* Bg = (const short*)Bw + (size_t)(bn * BN + srow) * K + scol;

    f32x4 acc[2][2][4][JF];
#pragma unroll
    for (int qr = 0; qr < 2; qr++)
#pragma unroll
        for (int qc = 0; qc < 2; qc++)
#pragma unroll
            for (int i = 0; i < 4; i++)
#pragma unroll
                for (int j = 0; j < JF; j++) acc[qr][qc][i][j] = (f32x4){0.f, 0.f, 0.f, 0.f};

#define STAGE_A(b, k0)                                                              \
    do {                                                                            \
        _Pragma("unroll") for (int s = 0; s < 4; s++)                               \
            gl_lds16(Ag + (size_t)s * 64 * K + (k0), &As[b][(s * 64 + wid * 8) * 64]); \
    } while (0)
#define STAGE_B(b, k0)                                                              \
    do {                                                                            \
        _Pragma("unroll") for (int s = 0; s < BISS; s++)                            \
            gl_lds16(Bg + (size_t)s * 64 * K + (k0), &Bs[b][(s * 64 + wid * 8) * 64]); \
    } while (0)

#define RD_A(b, R, q) (*(const short8*)&As[b][(R) * 64 + (((q) ^ ((R) & 7)) * 8)])
#define RD_B(b, R, q) (*(const short8*)&Bs[b][(R) * 64 + (((q) ^ ((R) & 7)) * 8)])
#define LGKM0()                                          \
    do {                                                 \
        asm volatile("s_waitcnt lgkmcnt(0)" ::: "memory"); \
        __builtin_amdgcn_sched_barrier(0);               \
    } while (0)

    STAGE_A(0, 0);
    STAGE_B(0, 0);

    const int NT = K / 64;
    for (int t = 0; t < NT; t++) {
        const int p = t & 1;
        asm volatile("s_waitcnt vmcnt(0)" ::: "memory");
        __builtin_amdgcn_s_barrier();
        __builtin_amdgcn_sched_barrier(0);
        const int kn = (t + 1) * 64;
        const bool more = t + 1 < NT;

        short8 afr[4][2], bfr[JF][2];

#pragma unroll
        for (int i = 0; i < 4; i++)
#pragma unroll
            for (int kq = 0; kq < 2; kq++)
                afr[i][kq] = RD_A(p, wr * 128 + i * 16 + lrow, kq * 4 + quad);
#pragma unroll
        for (int j = 0; j < JF; j++)
#pragma unroll
            for (int kq = 0; kq < 2; kq++)
                bfr[j][kq] = RD_B(p, wc * WN + j * 16 + lrow, kq * 4 + quad);
        if (more) STAGE_A(p ^ 1, kn);
        LGKM0();
        __builtin_amdgcn_s_setprio(1);
#pragma unroll
        for (int i = 0; i < 4; i++)
#pragma unroll
            for (int j = 0; j < JF; j++)
#pragma unroll
                for (int kq = 0; kq < 2; kq++)
                    acc[0][0][i][j] = __builtin_amdgcn_mfma_f32_16x16x32_bf16(
                        afr[i][kq], bfr[j][kq], acc[0][0][i][j], 0, 0, 0);
        __builtin_amdgcn_s_setprio(0);
        __builtin_amdgcn_s_barrier();

#pragma unroll
        for (int j = 0; j < JF; j++)
#pragma unroll
            for (int kq = 0; kq < 2; kq++)
                bfr[j][kq] = RD_B(p, wc * WN + WN / 2 + j * 16 + lrow, kq * 4 + quad);
        if (more) STAGE_B(p ^ 1, kn);
        LGKM0();
        __builtin_amdgcn_s_setprio(1);
#pragma unroll
        for (int i = 0; i < 4; i++)
#pragma unroll
            for (int j = 0; j < JF; j++)
#pragma unroll
                for (int kq = 0; kq < 2; kq++)
                    acc[0][1][i][j] = __builtin_amdgcn_mfma_f32_16x16x32_bf16(
                        afr[i][kq], bfr[j][kq], acc[0][1][i][j], 0, 0, 0);
        __builtin_amdgcn_s_setprio(0);
        __builtin_amdgcn_s_barrier();

#pragma unroll
        for (int i = 0; i < 4; i++)
#pragma unroll
            for (int kq = 0; kq < 2; kq++)
                afr[i][kq] = RD_A(p, wr * 128 + 64 + i * 16 + lrow, kq * 4 + quad);
        LGKM0();
        __builtin_amdgcn_s_setprio(1);
#pragma unroll
        for (int i = 0; i < 4; i++)
#pragma unroll
            for (int j = 0; j < JF; j++)
#pragma unroll
                for (int kq = 0; kq < 2; kq++)
                    acc[1][1][i][j] = __builtin_amdgcn_mfma_f32_16x16x32_bf16(
                        afr[i][kq], bfr[j][kq], acc[1][1][i][j], 0, 0, 0);
        __builtin_amdgcn_s_setprio(0);
        __builtin_amdgcn_s_barrier();

#pragma unroll
        for (int j = 0; j < JF; j++)
#pragma unroll
            for (int kq = 0; kq < 2; kq++)
                bfr[j][kq] = RD_B(p, wc * WN + j * 16 + lrow, kq * 4 + quad);
        LGKM0();
        __builtin_amdgcn_s_setprio(1);
#pragma unroll
        for (int i = 0; i < 4; i++)
#pragma unroll
            for (int j = 0; j < JF; j++)
#pragma unroll
                for (int kq = 0; kq < 2; kq++)
                    acc[1][0][i][j] = __builtin_amdgcn_mfma_f32_16x16x32_bf16(
                        afr[i][kq], bfr[j][kq], acc[1][0][i][j], 0, 0, 0);
        __builtin_amdgcn_s_setprio(0);
    }
#undef STAGE_A
#undef STAGE_B
#undef RD_A
#undef RD_B
#undef LGKM0

#pragma unroll
    for (int qr = 0; qr < 2; qr++)
#pragma unroll
        for (int qc = 0; qc < 2; qc++)
#pragma unroll
            for (int i = 0; i < 4; i++)
#pragma unroll
                for (int j = 0; j < JF; j++) {
                    int col = bn * BN + wc * WN + qc * (WN / 2) + j * 16 + lrow;
                    float bv = bias[col];
#pragma unroll
                    for (int r = 0; r < 4; r++) {
                        int row = bm * 256 + wr * 128 + qr * 64 + i * 16 + quad * 4 + r;
                        float v = acc[qr][qc][i][j][r] + bv;
                        if (EPI == 0) {
                            v = fmaxf(v, 0.f);
                            ((bf16*)Cout)[(size_t)row * N + col] = __float2bfloat16(v);
                        } else if (EPI == 1) {
                            ((float*)Cout)[(size_t)row * N + col] = v;
                        } else {
                            v += RES[(size_t)row * N + col];
                            ((float*)Cout)[(size_t)row * N + col] = v;
                        }
                    }
                }
}

// ---------------- gemm2: 256x128 tile, 8 waves 4Mx2N, 3-deep buffers, counted vmcnt ----------------
__global__ __launch_bounds__(512, 1) void gemm2_k(const bf16* __restrict__ A,
                                                  const bf16* __restrict__ Bw,
                                                  const float* __restrict__ bias,
                                                  const float* __restrict__ RES,
                                                  float* __restrict__ Cout,
                                                  int M, int N, int K) {
    __shared__ short As[3][256 * 64];
    __shared__ short Bs[3][128 * 64];

    const int tid = threadIdx.x;
    const int wid = tid >> 6, lane = tid & 63;
    const int wr = wid >> 1, wc = wid & 1;       // 4M x 2N waves, 64x64 out each
    const int lrow = lane & 15, quad = lane >> 4;

    const int nbx = gridDim.x;
    const int id = blockIdx.y * nbx + blockIdx.x;
    const int chunk = (nbx * gridDim.y) >> 3;
    const int swz = (id & 7) * chunk + (id >> 3);
    const int bn = swz % nbx, bm = swz / nbx;

    const int srow = wid * 8 + (lane >> 3);
    const int scol = ((lane & 7) ^ ((lane >> 3) & 7)) * 8;   // pre-permuted source (T2, rule 21)
    const short* Ag = (const short*)A + (size_t)(bm * 256 + srow) * K + scol;
    const short* Bg = (const short*)Bw + (size_t)(bn * 128 + srow) * K + scol;

    f32x4 acc[4][4];
#pragma unroll
    for (int i = 0; i < 4; i++)
#pragma unroll
        for (int j = 0; j < 4; j++) acc[i][j] = (f32x4){0.f, 0.f, 0.f, 0.f};

#define STAGE2_A(dst, k0)                                                            \
    do {                                                                             \
        _Pragma("unroll") for (int s = 0; s < 4; s++)                                \
            gl_lds16(Ag + (size_t)s * 64 * K + (k0), (dst) + (s * 64 + wid * 8) * 64); \
    } while (0)
#define STAGE2_B(dst, k0)                                                            \
    do {                                                                             \
        _Pragma("unroll") for (int s = 0; s < 2; s++)                                \
            gl_lds16(Bg + (size_t)s * 64 * K + (k0), (dst) + (s * 64 + wid * 8) * 64); \
    } while (0)
#define RD2(base, R, q) (*(const short8*)&(base)[(R) * 64 + (((q) ^ ((R) & 7)) * 8)])
#define LGKM0()                                            \
    do {                                                   \
        asm volatile("s_waitcnt lgkmcnt(0)" ::: "memory"); \
        __builtin_amdgcn_sched_barrier(0);                 \
    } while (0)

    short* a0 = &As[0][0];
    short* a1 = &As[1][0];
    short* a2 = &As[2][0];
    short* b0 = &Bs[0][0];
    short* b1 = &Bs[1][0];
    short* b2 = &Bs[2][0];

    STAGE2_A(a0, 0);
    STAGE2_B(b0, 0);
    STAGE2_A(a1, 64);
    STAGE2_B(b1, 64);

    const int NT = K / 64;
    for (int t = 0; t < NT; t++) {
        if (t < NT - 1)
            asm volatile("s_waitcnt vmcnt(6)" ::: "memory");
        else
            asm volatile("s_waitcnt vmcnt(0)" ::: "memory");
        __builtin_amdgcn_s_barrier();
        __builtin_amdgcn_sched_barrier(0);
        const bool more = t + 2 < NT;
        const int kn = (t + 2) * 64;

        short8 afr[4][2], bfr[4][2];
#pragma unroll
        for (int i = 0; i < 4; i++)
#pragma unroll
            for (int kq = 0; kq < 2; kq++)
                afr[i][kq] = RD2(a0, wr * 64 + i * 16 + lrow, kq * 4 + quad);
#pragma unroll
        for (int j = 0; j < 2; j++)
#pragma unroll
            for (int kq = 0; kq < 2; kq++)
                bfr[j][kq] = RD2(b0, wc * 64 + j * 16 + lrow, kq * 4 + quad);
        if (more) STAGE2_A(a2, kn);
        LGKM0();
        __builtin_amdgcn_s_setprio(1);
#pragma unroll
        for (int i = 0; i < 4; i++)
#pragma unroll
            for (int j = 0; j < 2; j++)
#pragma unroll
                for (int kq = 0; kq < 2; kq++)
                    acc[i][j] = __builtin_amdgcn_mfma_f32_16x16x32_bf16(
                        afr[i][kq], bfr[j][kq], acc[i][j], 0, 0, 0);
        __builtin_amdgcn_s_setprio(0);

#pragma unroll
        for (int j = 2; j < 4; j++)
#pragma unroll
            for (int kq = 0; kq < 2; kq++)
                bfr[j][kq] = RD2(b0, wc * 64 + j * 16 + lrow, kq * 4 + quad);
        if (more) STAGE2_B(b2, kn);
        LGKM0();
        __builtin_amdgcn_s_setprio(1);
#pragma unroll
        for (int i = 0; i < 4; i++)
#pragma unroll
            for (int j = 2; j < 4; j++)
#pragma unroll
                for (int kq = 0; kq < 2; kq++)
                    acc[i][j] = __builtin_amdgcn_mfma_f32_16x16x32_bf16(
                        afr[i][kq], bfr[j][kq], acc[i][j], 0, 0, 0);
        __builtin_amdgcn_s_setprio(0);

        short* ta = a0; a0 = a1; a1 = a2; a2 = ta;
        short* tb = b0; b0 = b1; b1 = b2; b2 = tb;
    }
#undef STAGE2_A
#undef STAGE2_B
#undef RD2
#undef LGKM0

#pragma unroll
    for (int i = 0; i < 4; i++)
#pragma unroll
        for (int j = 0; j < 4; j++) {
            int col = bn * 128 + wc * 64 + j * 16 + lrow;
            float bv = bias[col];
#pragma unroll
            for (int r = 0; r < 4; r++) {
                int row = bm * 256 + wr * 64 + i * 16 + quad * 4 + r;
                float v = acc[i][j][r] + bv + RES[(size_t)row * N + col];
                Cout[(size_t)row * N + col] = v;
            }
        }
}

// ---------------- launch ----------------
extern "C" void kernel_launch(void* const* d_in, const int* in_sizes, int n_in,
                              void* d_out, int out_size, void* d_ws, size_t ws_size,
                              hipStream_t stream) {
    const float* x = (const float*)d_in[0];
    const float* w1 = (const float*)d_in[1];
    const float* b1 = (const float*)d_in[2];
    const float* w2 = (const float*)d_in[3];
    const float* b2 = (const float*)d_in[4];
    const float* g1 = (const float*)d_in[5];
    const float* be1 = (const float*)d_in[6];
    const float* g2 = (const float*)d_in[7];
    const float* be2 = (const float*)d_in[8];
    float* out = (float*)d_out;

    char* ws = (char*)d_ws;
    const size_t MB = 1024 * 1024;
    float* attn_out = (float*)(ws);            // 32 MiB
    float* x1 = (float*)(ws + 32 * MB);        // 32 MiB
    bf16* x1b = (bf16*)(ws + 64 * MB);         // 16 MiB
    bf16* w1b = (bf16*)(ws + 80 * MB);         // 8 MiB
    bf16* w2b = (bf16*)(ws + 88 * MB);         // 8 MiB
    bf16* hb = (bf16*)(ws + 96 * MB);          // 64 MiB (GEMM phase)
    // attention-phase buffers alias hb's region (dead once gemm1 runs):
    short* xb = (short*)(ws + 96 * MB);        // 16 MiB bf16 x
    short* vt = (short*)(ws + 112 * MB);       // 16 MiB bf16 x^T per (b,h)
    float* y2 = attn_out;                      // reuse

    convert_bf16_kernel<<<4096, 256, 0, stream>>>(w1, w1b, F_ * D_);
    convert_bf16_kernel<<<4096, 256, 0, stream>>>(w2, w2b, D_ * F_);
    transpose_vt_kernel<<<dim3(B_ * H_, L_ / 64), 256, 0, stream>>>(x, vt, xb);

    flash_attn_kernel<<<B_ * H_ * (L_ / 128), 256, 0, stream>>>(x, xb, vt, attn_out);

    ln_kernel<<<B_ * L_, 256, 0, stream>>>(x, attn_out, g1, be1, x1, x1b);

    // gemm1: M=8192, N=4096, K=1024 -> grid 16 x 32 = 512 wg
    gemm8p<0, 256><<<dim3(F_ / 256, (B_ * L_) / 256), 512, 0, stream>>>(
        x1b, w1b, b1, nullptr, (void*)hb, B_ * L_, F_, D_);
    // gemm2: M=8192, N=1024, K=4096 -> grid 8 x 32 = 256 wg (1/CU), 3-deep pipeline
    gemm2_k<<<dim3(D_ / 128, (B_ * L_) / 256), 512, 0, stream>>>(
        hb, w2b, b2, x1, y2, B_ * L_, D_, F_);

    ln_kernel<<<B_ * L_, 256, 0, stream>>>(y2, nullptr, g2, be2, out, nullptr);
}